// Round 1
// baseline (829.023 us; speedup 1.0000x reference)
//
#include <hip/hip_runtime.h>

#define HID 96
#define INDIM 128
#define OUTDIM 10

// ---------------- CSR build ----------------
__global__ void k_count(const int* __restrict__ dst, int E, int* __restrict__ cnt) {
  int i = blockIdx.x * 256 + threadIdx.x;
  if (i < E) atomicAdd(&cnt[dst[i]], 1);
}

__global__ void k_dinv(const int* __restrict__ cnt, float* __restrict__ dinv, int n) {
  int i = blockIdx.x * 256 + threadIdx.x;
  if (i < n) dinv[i] = rsqrtf((float)cnt[i] + 1.0f);
}

__global__ __launch_bounds__(1024) void k_scan(const int* __restrict__ cnt,
                                               int* __restrict__ rowp, int n) {
  __shared__ int sums[1024];
  int t = threadIdx.x;
  int per = (n + 1023) / 1024;
  int base = t * per;
  int s = 0;
  for (int i = 0; i < per; ++i) { int idx = base + i; if (idx < n) s += cnt[idx]; }
  int mine = s;
  sums[t] = s;
  __syncthreads();
  for (int off = 1; off < 1024; off <<= 1) {
    int v = 0;
    if (t >= off) v = sums[t - off];
    __syncthreads();
    if (t >= off) sums[t] += v;
    __syncthreads();
  }
  int run = sums[t] - mine;  // exclusive prefix for this thread's chunk
  for (int i = 0; i < per; ++i) {
    int idx = base + i;
    if (idx < n) { rowp[idx] = run; run += cnt[idx]; }
  }
  if (t == 1023) rowp[n] = sums[1023];
}

__global__ void k_fill(const int* __restrict__ src, const int* __restrict__ dst, int E,
                       const int* __restrict__ rowp, int* __restrict__ cursor,
                       int* __restrict__ csr) {
  int i = blockIdx.x * 256 + threadIdx.x;
  if (i < E) {
    int d = dst[i];
    int pos = atomicAdd(&cursor[d], 1);
    csr[rowp[d] + pos] = src[i];
  }
}

// ---------------- GEMM: out[M x 96] = A[M x K] @ W[K x 96] (+bias)(+relu) ----------------
// Block: 256 threads, 64-row tile, full N=96. W fully LDS-resident.
// Thread (tr,tc) in 16x16 grid computes 4 rows x 6 cols in registers.
template <int K, bool RELU>
__global__ __launch_bounds__(256) void gemm96k(const float* __restrict__ A,
                                               const float* __restrict__ W,
                                               const float* __restrict__ bias,
                                               float* __restrict__ out, int M) {
  constexpr int APAD = (K == 128) ? 132 : 100;  // pad: 4*APAD % 32 == 16 -> free 2-way
  __shared__ float wL[K * 96];
  __shared__ float aL[64 * APAD];

  int t = threadIdx.x;
  int row0 = blockIdx.x * 64;

  // stage W (contiguous) as float4
  const int W4 = K * 96 / 4;
  float4* wf = (float4*)wL;
  const float4* wg = (const float4*)W;
  for (int i = t; i < W4; i += 256) wf[i] = wg[i];

  // stage A tile (rows contiguous in global) as float4, guard tail rows with 0
  const int A4 = K / 4;
  for (int i = t; i < 64 * A4; i += 256) {
    int r = i / A4, c4 = i % A4;
    float4 v = make_float4(0.f, 0.f, 0.f, 0.f);
    int gr = row0 + r;
    if (gr < M) v = ((const float4*)(A + (size_t)gr * K))[c4];
    *(float4*)&aL[r * APAD + c4 * 4] = v;
  }
  __syncthreads();

  int tr = t >> 4;   // 0..15
  int tc = t & 15;   // 0..15
  float acc[4][6];
#pragma unroll
  for (int i = 0; i < 4; ++i)
#pragma unroll
    for (int j = 0; j < 6; ++j) acc[i][j] = 0.f;

  const float* a0p = &aL[(tr * 4 + 0) * APAD];
  const float* a1p = &aL[(tr * 4 + 1) * APAD];
  const float* a2p = &aL[(tr * 4 + 2) * APAD];
  const float* a3p = &aL[(tr * 4 + 3) * APAD];
  const float* wp = &wL[tc * 6];

#pragma unroll 8
  for (int k = 0; k < K; ++k) {
    float av0 = a0p[k], av1 = a1p[k], av2 = a2p[k], av3 = a3p[k];
    float b0 = wp[(size_t)k * 96 + 0];
    float b1 = wp[(size_t)k * 96 + 1];
    float b2 = wp[(size_t)k * 96 + 2];
    float b3 = wp[(size_t)k * 96 + 3];
    float b4 = wp[(size_t)k * 96 + 4];
    float b5 = wp[(size_t)k * 96 + 5];
    acc[0][0] += av0 * b0; acc[0][1] += av0 * b1; acc[0][2] += av0 * b2;
    acc[0][3] += av0 * b3; acc[0][4] += av0 * b4; acc[0][5] += av0 * b5;
    acc[1][0] += av1 * b0; acc[1][1] += av1 * b1; acc[1][2] += av1 * b2;
    acc[1][3] += av1 * b3; acc[1][4] += av1 * b4; acc[1][5] += av1 * b5;
    acc[2][0] += av2 * b0; acc[2][1] += av2 * b1; acc[2][2] += av2 * b2;
    acc[2][3] += av2 * b3; acc[2][4] += av2 * b4; acc[2][5] += av2 * b5;
    acc[3][0] += av3 * b0; acc[3][1] += av3 * b1; acc[3][2] += av3 * b2;
    acc[3][3] += av3 * b3; acc[3][4] += av3 * b4; acc[3][5] += av3 * b5;
  }

#pragma unroll
  for (int i = 0; i < 4; ++i) {
    int r = row0 + tr * 4 + i;
    if (r < M) {
#pragma unroll
      for (int j = 0; j < 6; ++j) {
        int c = tc * 6 + j;
        float v = acc[i][j] + (bias ? bias[c] : 0.f);
        if (RELU) v = fmaxf(v, 0.f);
        out[(size_t)r * 96 + c] = v;
      }
    }
  }
}

// ---------------- GCN aggregation ----------------
// One wave per node. lane l owns dims l and l+64 (l<32).
// out[i] = relu(dinv[i]*sum_e(hw[src]*dinv[src]) + hw[i]*dinv[i]^2 + bias)
__global__ __launch_bounds__(256) void k_agg(const float* __restrict__ hw,
                                             const int* __restrict__ rowp,
                                             const int* __restrict__ csr,
                                             const float* __restrict__ dinv,
                                             const float* __restrict__ bias,
                                             float* __restrict__ out, int n) {
  int wave = threadIdx.x >> 6;
  int lane = threadIdx.x & 63;
  int node = blockIdx.x * 4 + wave;
  if (node >= n) return;
  int beg = rowp[node], end = rowp[node + 1];
  float acc0 = 0.f, acc1 = 0.f;
  for (int e = beg; e < end; ++e) {
    int s = csr[e];
    float wgt = dinv[s];
    const float* row = hw + (size_t)s * HID;
    acc0 += row[lane] * wgt;
    if (lane < 32) acc1 += row[64 + lane] * wgt;
  }
  float di = dinv[node];
  float selfw = di * di;
  const float* srow = hw + (size_t)node * HID;
  float r0 = di * acc0 + srow[lane] * selfw + bias[lane];
  out[(size_t)node * HID + lane] = fmaxf(r0, 0.f);
  if (lane < 32) {
    float r1 = di * acc1 + srow[64 + lane] * selfw + bias[64 + lane];
    out[(size_t)node * HID + 64 + lane] = fmaxf(r1, 0.f);
  }
}

// ---------------- global add pool (batch sorted) ----------------
__global__ __launch_bounds__(128) void k_pool(const float* __restrict__ h,
                                              const int* __restrict__ batch, int n,
                                              float* __restrict__ g) {
  int gr = blockIdx.x;
  int d = threadIdx.x;
  int lo = 0, hi = n;
  while (lo < hi) { int m = (lo + hi) >> 1; if (batch[m] < gr) lo = m + 1; else hi = m; }
  int start = lo;
  hi = n;
  while (lo < hi) { int m = (lo + hi) >> 1; if (batch[m] < gr + 1) lo = m + 1; else hi = m; }
  int end = lo;
  if (d < HID) {
    float s = 0.f;
    for (int i = start; i < end; ++i) s += h[(size_t)i * HID + d];
    g[gr * HID + d] = s;
  }
}

// ---------------- decoder layer 2 (512x96 @ 96x10 + b) ----------------
__global__ void k_dec2(const float* __restrict__ g2, const float* __restrict__ W,
                       const float* __restrict__ b, float* __restrict__ out, int G) {
  int idx = blockIdx.x * 256 + threadIdx.x;
  if (idx >= G * OUTDIM) return;
  int r = idx / OUTDIM, c = idx % OUTDIM;
  float s = b[c];
  const float* row = g2 + (size_t)r * HID;
  for (int k = 0; k < HID; ++k) s += row[k] * W[k * OUTDIM + c];
  out[idx] = s;
}

extern "C" void kernel_launch(void* const* d_in, const int* in_sizes, int n_in,
                              void* d_out, int out_size, void* d_ws, size_t ws_size,
                              hipStream_t stream) {
  const float* x     = (const float*)d_in[0];
  const int*   ei    = (const int*)d_in[1];
  const int*   batch = (const int*)d_in[2];
  const float* encW0 = (const float*)d_in[3];
  const float* encb0 = (const float*)d_in[4];
  const float* encW1 = (const float*)d_in[5];
  const float* encb1 = (const float*)d_in[6];
  const float* convW = (const float*)d_in[7];
  const float* convb = (const float*)d_in[8];
  const float* decW0 = (const float*)d_in[9];
  const float* decb0 = (const float*)d_in[10];
  const float* decW1 = (const float*)d_in[11];
  const float* decb1 = (const float*)d_in[12];
  float* out = (float*)d_out;

  int n  = in_sizes[0] / INDIM;
  int E  = in_sizes[1] / 2;
  int G  = out_size / OUTDIM;
  int NC = in_sizes[7] / (HID * HID);

  const int* srcI = ei;
  const int* dstI = ei + E;

  char* w = (char*)d_ws;
  auto alloc = [&](size_t bytes) {
    char* p = w;
    w += (bytes + 255) & ~(size_t)255;
    return p;
  };
  float* bufA  = (float*)alloc((size_t)n * HID * 4);
  float* bufB  = (float*)alloc((size_t)n * HID * 4);
  int*   cnt   = (int*)alloc((size_t)n * 4);
  int*   cursor= (int*)alloc((size_t)n * 4);
  int*   rowp  = (int*)alloc((size_t)(n + 1) * 4);
  int*   csr   = (int*)alloc((size_t)E * 4);
  float* dinv  = (float*)alloc((size_t)n * 4);
  float* g1    = (float*)alloc((size_t)G * HID * 4);
  float* g2    = (float*)alloc((size_t)G * HID * 4);

  hipMemsetAsync(cnt, 0, (size_t)n * 4, stream);
  hipMemsetAsync(cursor, 0, (size_t)n * 4, stream);

  int eb = (E + 255) / 256;
  k_count<<<eb, 256, 0, stream>>>(dstI, E, cnt);
  k_dinv<<<(n + 255) / 256, 256, 0, stream>>>(cnt, dinv, n);
  k_scan<<<1, 1024, 0, stream>>>(cnt, rowp, n);
  k_fill<<<eb, 256, 0, stream>>>(srcI, dstI, E, rowp, cursor, csr);

  int gb = (n + 63) / 64;
  // encoder
  gemm96k<128, true><<<gb, 256, 0, stream>>>(x, encW0, encb0, bufA, n);
  gemm96k<96, false><<<gb, 256, 0, stream>>>(bufA, encW1, encb1, bufB, n);
  // convs: h lives in bufB, hw in bufA
  for (int l = 0; l < NC; ++l) {
    gemm96k<96, false><<<gb, 256, 0, stream>>>(bufB, convW + (size_t)l * HID * HID,
                                               nullptr, bufA, n);
    k_agg<<<(n + 3) / 4, 256, 0, stream>>>(bufA, rowp, csr, dinv,
                                           convb + (size_t)l * HID, bufB, n);
  }
  // pool + decoder
  k_pool<<<G, 128, 0, stream>>>(bufB, batch, n, g1);
  gemm96k<96, true><<<(G + 63) / 64, 256, 0, stream>>>(g1, decW0, decb0, g2, G);
  k_dec2<<<(G * OUTDIM + 255) / 256, 256, 0, stream>>>(g2, decW1, decb1, out, G);
}

// Round 2
// 745.930 us; speedup vs baseline: 1.1114x; 1.1114x over previous
//
#include <hip/hip_runtime.h>

#define HID 96
#define INDIM 128
#define OUTDIM 10

// ---------------- CSR build ----------------
__global__ void k_count(const int* __restrict__ dst, int E, int* __restrict__ cnt) {
  int i = blockIdx.x * 256 + threadIdx.x;
  if (i < E) atomicAdd(&cnt[dst[i]], 1);
}

__global__ void k_dinv(const int* __restrict__ cnt, float* __restrict__ dinv, int n) {
  int i = blockIdx.x * 256 + threadIdx.x;
  if (i < n) dinv[i] = rsqrtf((float)cnt[i] + 1.0f);
}

// ---- two-level scan: A) per-block (512 elem) sums, B) scan 98 block sums, C) local scan+offset
__global__ __launch_bounds__(256) void k_scanA(const int* __restrict__ cnt, int n,
                                               int* __restrict__ bsum) {
  __shared__ int red[256];
  int b = blockIdx.x, t = threadIdx.x;
  int base = b * 512;
  int v = 0;
  int i0 = base + t, i1 = base + 256 + t;
  if (i0 < n) v += cnt[i0];
  if (i1 < n) v += cnt[i1];
  red[t] = v;
  __syncthreads();
  for (int off = 128; off > 0; off >>= 1) {
    if (t < off) red[t] += red[t + off];
    __syncthreads();
  }
  if (t == 0) bsum[b] = red[0];
}

__global__ __launch_bounds__(256) void k_scanB(const int* __restrict__ bsum, int nb,
                                               int* __restrict__ boff,
                                               int* __restrict__ rowp, int n) {
  __shared__ int s[256];
  int t = threadIdx.x;
  int v = (t < nb) ? bsum[t] : 0;
  s[t] = v;
  __syncthreads();
  for (int off = 1; off < 256; off <<= 1) {
    int u = (t >= off) ? s[t - off] : 0;
    __syncthreads();
    s[t] += u;
    __syncthreads();
  }
  if (t < nb) boff[t] = s[t] - v;           // exclusive prefix of block sums
  if (t == 255) rowp[n] = s[255];           // total edge count
}

__global__ __launch_bounds__(256) void k_scanC(const int* __restrict__ cnt, int n,
                                               const int* __restrict__ boff,
                                               int* __restrict__ rowp) {
  __shared__ int s[256];
  int b = blockIdx.x, t = threadIdx.x;
  int base = b * 512;
  int i0 = base + 2 * t, i1 = i0 + 1;
  int c0 = (i0 < n) ? cnt[i0] : 0;
  int c1 = (i1 < n) ? cnt[i1] : 0;
  int pair = c0 + c1;
  s[t] = pair;
  __syncthreads();
  for (int off = 1; off < 256; off <<= 1) {
    int u = (t >= off) ? s[t - off] : 0;
    __syncthreads();
    s[t] += u;
    __syncthreads();
  }
  int excl = s[t] - pair + boff[b];
  if (i0 < n) rowp[i0] = excl;
  if (i1 < n) rowp[i1] = excl + c0;
}

__global__ void k_fill(const int* __restrict__ src, const int* __restrict__ dst, int E,
                       const int* __restrict__ rowp, int* __restrict__ cursor,
                       int* __restrict__ csr) {
  int i = blockIdx.x * 256 + threadIdx.x;
  if (i < E) {
    int d = dst[i];
    int pos = atomicAdd(&cursor[d], 1);
    csr[rowp[d] + pos] = src[i];
  }
}

// ---------------- GEMM: out[M x 96] = A[M x K] @ W[K x 96] (+bias)(+relu) ----------------
template <int K, bool RELU>
__global__ __launch_bounds__(256) void gemm96k(const float* __restrict__ A,
                                               const float* __restrict__ W,
                                               const float* __restrict__ bias,
                                               float* __restrict__ out, int M) {
  constexpr int APAD = (K == 128) ? 132 : 100;  // pad: 4*APAD % 32 == 16 -> free 2-way
  __shared__ float wL[K * 96];
  __shared__ float aL[64 * APAD];

  int t = threadIdx.x;
  int row0 = blockIdx.x * 64;

  const int W4 = K * 96 / 4;
  float4* wf = (float4*)wL;
  const float4* wg = (const float4*)W;
  for (int i = t; i < W4; i += 256) wf[i] = wg[i];

  const int A4 = K / 4;
  for (int i = t; i < 64 * A4; i += 256) {
    int r = i / A4, c4 = i % A4;
    float4 v = make_float4(0.f, 0.f, 0.f, 0.f);
    int gr = row0 + r;
    if (gr < M) v = ((const float4*)(A + (size_t)gr * K))[c4];
    *(float4*)&aL[r * APAD + c4 * 4] = v;
  }
  __syncthreads();

  int tr = t >> 4;
  int tc = t & 15;
  float acc[4][6];
#pragma unroll
  for (int i = 0; i < 4; ++i)
#pragma unroll
    for (int j = 0; j < 6; ++j) acc[i][j] = 0.f;

  const float* a0p = &aL[(tr * 4 + 0) * APAD];
  const float* a1p = &aL[(tr * 4 + 1) * APAD];
  const float* a2p = &aL[(tr * 4 + 2) * APAD];
  const float* a3p = &aL[(tr * 4 + 3) * APAD];
  const float* wp = &wL[tc * 6];

#pragma unroll 8
  for (int k = 0; k < K; ++k) {
    float av0 = a0p[k], av1 = a1p[k], av2 = a2p[k], av3 = a3p[k];
    float b0 = wp[(size_t)k * 96 + 0];
    float b1 = wp[(size_t)k * 96 + 1];
    float b2 = wp[(size_t)k * 96 + 2];
    float b3 = wp[(size_t)k * 96 + 3];
    float b4 = wp[(size_t)k * 96 + 4];
    float b5 = wp[(size_t)k * 96 + 5];
    acc[0][0] += av0 * b0; acc[0][1] += av0 * b1; acc[0][2] += av0 * b2;
    acc[0][3] += av0 * b3; acc[0][4] += av0 * b4; acc[0][5] += av0 * b5;
    acc[1][0] += av1 * b0; acc[1][1] += av1 * b1; acc[1][2] += av1 * b2;
    acc[1][3] += av1 * b3; acc[1][4] += av1 * b4; acc[1][5] += av1 * b5;
    acc[2][0] += av2 * b0; acc[2][1] += av2 * b1; acc[2][2] += av2 * b2;
    acc[2][3] += av2 * b3; acc[2][4] += av2 * b4; acc[2][5] += av2 * b5;
    acc[3][0] += av3 * b0; acc[3][1] += av3 * b1; acc[3][2] += av3 * b2;
    acc[3][3] += av3 * b3; acc[3][4] += av3 * b4; acc[3][5] += av3 * b5;
  }

#pragma unroll
  for (int i = 0; i < 4; ++i) {
    int r = row0 + tr * 4 + i;
    if (r < M) {
#pragma unroll
      for (int j = 0; j < 6; ++j) {
        int c = tc * 6 + j;
        float v = acc[i][j] + (bias ? bias[c] : 0.f);
        if (RELU) v = fmaxf(v, 0.f);
        out[(size_t)r * 96 + c] = v;
      }
    }
  }
}

// ---------------- GCN aggregation ----------------
__global__ __launch_bounds__(256) void k_agg(const float* __restrict__ hw,
                                             const int* __restrict__ rowp,
                                             const int* __restrict__ csr,
                                             const float* __restrict__ dinv,
                                             const float* __restrict__ bias,
                                             float* __restrict__ out, int n) {
  int wave = threadIdx.x >> 6;
  int lane = threadIdx.x & 63;
  int node = blockIdx.x * 4 + wave;
  if (node >= n) return;
  int beg = rowp[node], end = rowp[node + 1];
  float acc0 = 0.f, acc1 = 0.f;
  for (int e = beg; e < end; ++e) {
    int s = csr[e];
    float wgt = dinv[s];
    const float* row = hw + (size_t)s * HID;
    acc0 += row[lane] * wgt;
    if (lane < 32) acc1 += row[64 + lane] * wgt;
  }
  float di = dinv[node];
  float selfw = di * di;
  const float* srow = hw + (size_t)node * HID;
  float r0 = di * acc0 + srow[lane] * selfw + bias[lane];
  out[(size_t)node * HID + lane] = fmaxf(r0, 0.f);
  if (lane < 32) {
    float r1 = di * acc1 + srow[64 + lane] * selfw + bias[64 + lane];
    out[(size_t)node * HID + 64 + lane] = fmaxf(r1, 0.f);
  }
}

// ---------------- global add pool (batch sorted) ----------------
__global__ __launch_bounds__(128) void k_pool(const float* __restrict__ h,
                                              const int* __restrict__ batch, int n,
                                              float* __restrict__ g) {
  int gr = blockIdx.x;
  int d = threadIdx.x;
  int lo = 0, hi = n;
  while (lo < hi) { int m = (lo + hi) >> 1; if (batch[m] < gr) lo = m + 1; else hi = m; }
  int start = lo;
  hi = n;
  while (lo < hi) { int m = (lo + hi) >> 1; if (batch[m] < gr + 1) lo = m + 1; else hi = m; }
  int end = lo;
  if (d < HID) {
    float s = 0.f;
    for (int i = start; i < end; ++i) s += h[(size_t)i * HID + d];
    g[gr * HID + d] = s;
  }
}

// ---------------- decoder layer 2 ----------------
__global__ void k_dec2(const float* __restrict__ g2, const float* __restrict__ W,
                       const float* __restrict__ b, float* __restrict__ out, int G) {
  int idx = blockIdx.x * 256 + threadIdx.x;
  if (idx >= G * OUTDIM) return;
  int r = idx / OUTDIM, c = idx % OUTDIM;
  float s = b[c];
  const float* row = g2 + (size_t)r * HID;
  for (int k = 0; k < HID; ++k) s += row[k] * W[k * OUTDIM + c];
  out[idx] = s;
}

extern "C" void kernel_launch(void* const* d_in, const int* in_sizes, int n_in,
                              void* d_out, int out_size, void* d_ws, size_t ws_size,
                              hipStream_t stream) {
  const float* x     = (const float*)d_in[0];
  const int*   ei    = (const int*)d_in[1];
  const int*   batch = (const int*)d_in[2];
  const float* encW0 = (const float*)d_in[3];
  const float* encb0 = (const float*)d_in[4];
  const float* encW1 = (const float*)d_in[5];
  const float* encb1 = (const float*)d_in[6];
  const float* convW = (const float*)d_in[7];
  const float* convb = (const float*)d_in[8];
  const float* decW0 = (const float*)d_in[9];
  const float* decb0 = (const float*)d_in[10];
  const float* decW1 = (const float*)d_in[11];
  const float* decb1 = (const float*)d_in[12];
  float* out = (float*)d_out;

  int n  = in_sizes[0] / INDIM;
  int E  = in_sizes[1] / 2;
  int G  = out_size / OUTDIM;
  int NC = in_sizes[7] / (HID * HID);

  const int* srcI = ei;
  const int* dstI = ei + E;

  char* w = (char*)d_ws;
  auto alloc = [&](size_t bytes) {
    char* p = w;
    w += (bytes + 255) & ~(size_t)255;
    return p;
  };
  float* bufA  = (float*)alloc((size_t)n * HID * 4);
  float* bufB  = (float*)alloc((size_t)n * HID * 4);
  int*   cnt   = (int*)alloc((size_t)n * 4);
  int*   cursor= (int*)alloc((size_t)n * 4);
  int*   rowp  = (int*)alloc((size_t)(n + 1) * 4);
  int*   csr   = (int*)alloc((size_t)E * 4);
  float* dinv  = (float*)alloc((size_t)n * 4);
  int*   bsum  = (int*)alloc(256 * 4);
  int*   boff  = (int*)alloc(256 * 4);
  float* g1    = (float*)alloc((size_t)G * HID * 4);
  float* g2    = (float*)alloc((size_t)G * HID * 4);

  hipMemsetAsync(cnt, 0, (size_t)n * 4, stream);
  hipMemsetAsync(cursor, 0, (size_t)n * 4, stream);

  int eb = (E + 255) / 256;
  int nb = (n + 511) / 512;
  k_count<<<eb, 256, 0, stream>>>(dstI, E, cnt);
  k_dinv<<<(n + 255) / 256, 256, 0, stream>>>(cnt, dinv, n);
  k_scanA<<<nb, 256, 0, stream>>>(cnt, n, bsum);
  k_scanB<<<1, 256, 0, stream>>>(bsum, nb, boff, rowp, n);
  k_scanC<<<nb, 256, 0, stream>>>(cnt, n, boff, rowp);
  k_fill<<<eb, 256, 0, stream>>>(srcI, dstI, E, rowp, cursor, csr);

  int gb = (n + 63) / 64;
  gemm96k<128, true><<<gb, 256, 0, stream>>>(x, encW0, encb0, bufA, n);
  gemm96k<96, false><<<gb, 256, 0, stream>>>(bufA, encW1, encb1, bufB, n);
  for (int l = 0; l < NC; ++l) {
    gemm96k<96, false><<<gb, 256, 0, stream>>>(bufB, convW + (size_t)l * HID * HID,
                                               nullptr, bufA, n);
    k_agg<<<(n + 3) / 4, 256, 0, stream>>>(bufA, rowp, csr, dinv,
                                           convb + (size_t)l * HID, bufB, n);
  }
  k_pool<<<G, 128, 0, stream>>>(bufB, batch, n, g1);
  gemm96k<96, true><<<(G + 63) / 64, 256, 0, stream>>>(g1, decW0, decb0, g2, G);
  k_dec2<<<(G * OUTDIM + 255) / 256, 256, 0, stream>>>(g2, decW1, decb1, out, G);
}

// Round 3
// 576.902 us; speedup vs baseline: 1.4370x; 1.2930x over previous
//
#include <hip/hip_runtime.h>

#define HID 96
#define INDIM 128
#define OUTDIM 10

// ---------------- CSR build ----------------
__global__ void k_count(const int* __restrict__ dst, int E, int* __restrict__ cnt) {
  int i = blockIdx.x * 256 + threadIdx.x;
  if (i < E) atomicAdd(&cnt[dst[i]], 1);
}

__global__ void k_dinv(const int* __restrict__ cnt, float* __restrict__ dinv, int n) {
  int i = blockIdx.x * 256 + threadIdx.x;
  if (i < n) dinv[i] = rsqrtf((float)cnt[i] + 1.0f);
}

// ---- two-level scan
__global__ __launch_bounds__(256) void k_scanA(const int* __restrict__ cnt, int n,
                                               int* __restrict__ bsum) {
  __shared__ int red[256];
  int b = blockIdx.x, t = threadIdx.x;
  int base = b * 512;
  int v = 0;
  int i0 = base + t, i1 = base + 256 + t;
  if (i0 < n) v += cnt[i0];
  if (i1 < n) v += cnt[i1];
  red[t] = v;
  __syncthreads();
  for (int off = 128; off > 0; off >>= 1) {
    if (t < off) red[t] += red[t + off];
    __syncthreads();
  }
  if (t == 0) bsum[b] = red[0];
}

__global__ __launch_bounds__(256) void k_scanB(const int* __restrict__ bsum, int nb,
                                               int* __restrict__ boff,
                                               int* __restrict__ rowp, int n) {
  __shared__ int s[256];
  int t = threadIdx.x;
  int v = (t < nb) ? bsum[t] : 0;
  s[t] = v;
  __syncthreads();
  for (int off = 1; off < 256; off <<= 1) {
    int u = (t >= off) ? s[t - off] : 0;
    __syncthreads();
    s[t] += u;
    __syncthreads();
  }
  if (t < nb) boff[t] = s[t] - v;
  if (t == 255) rowp[n] = s[255];
}

__global__ __launch_bounds__(256) void k_scanC(const int* __restrict__ cnt, int n,
                                               const int* __restrict__ boff,
                                               int* __restrict__ rowp) {
  __shared__ int s[256];
  int b = blockIdx.x, t = threadIdx.x;
  int base = b * 512;
  int i0 = base + 2 * t, i1 = i0 + 1;
  int c0 = (i0 < n) ? cnt[i0] : 0;
  int c1 = (i1 < n) ? cnt[i1] : 0;
  int pair = c0 + c1;
  s[t] = pair;
  __syncthreads();
  for (int off = 1; off < 256; off <<= 1) {
    int u = (t >= off) ? s[t - off] : 0;
    __syncthreads();
    s[t] += u;
    __syncthreads();
  }
  int excl = s[t] - pair + boff[b];
  if (i0 < n) rowp[i0] = excl;
  if (i1 < n) rowp[i1] = excl + c0;
}

__global__ void k_fill(const int* __restrict__ src, const int* __restrict__ dst, int E,
                       const int* __restrict__ rowp, int* __restrict__ cursor,
                       int* __restrict__ csr) {
  int i = blockIdx.x * 256 + threadIdx.x;
  if (i < E) {
    int d = dst[i];
    int pos = atomicAdd(&cursor[d], 1);
    csr[rowp[d] + pos] = src[i];
  }
}

// ---------------- GEMM: out[M x 96] = A[M x K] @ W[K x 96] (+bias)(+relu)(*rowscale) ----
template <int K, bool RELU>
__global__ __launch_bounds__(256) void gemm96k(const float* __restrict__ A,
                                               const float* __restrict__ W,
                                               const float* __restrict__ bias,
                                               const float* __restrict__ rowscale,
                                               float* __restrict__ out, int M) {
  constexpr int APAD = (K == 128) ? 132 : 100;
  __shared__ float wL[K * 96];
  __shared__ float aL[64 * APAD];

  int t = threadIdx.x;
  int row0 = blockIdx.x * 64;

  const int W4 = K * 96 / 4;
  float4* wf = (float4*)wL;
  const float4* wg = (const float4*)W;
  for (int i = t; i < W4; i += 256) wf[i] = wg[i];

  const int A4 = K / 4;
  for (int i = t; i < 64 * A4; i += 256) {
    int r = i / A4, c4 = i % A4;
    float4 v = make_float4(0.f, 0.f, 0.f, 0.f);
    int gr = row0 + r;
    if (gr < M) v = ((const float4*)(A + (size_t)gr * K))[c4];
    *(float4*)&aL[r * APAD + c4 * 4] = v;
  }
  __syncthreads();

  int tr = t >> 4;
  int tc = t & 15;
  float acc[4][6];
#pragma unroll
  for (int i = 0; i < 4; ++i)
#pragma unroll
    for (int j = 0; j < 6; ++j) acc[i][j] = 0.f;

  const float* a0p = &aL[(tr * 4 + 0) * APAD];
  const float* a1p = &aL[(tr * 4 + 1) * APAD];
  const float* a2p = &aL[(tr * 4 + 2) * APAD];
  const float* a3p = &aL[(tr * 4 + 3) * APAD];
  const float* wp = &wL[tc * 6];

#pragma unroll 8
  for (int k = 0; k < K; ++k) {
    float av0 = a0p[k], av1 = a1p[k], av2 = a2p[k], av3 = a3p[k];
    float b0 = wp[(size_t)k * 96 + 0];
    float b1 = wp[(size_t)k * 96 + 1];
    float b2 = wp[(size_t)k * 96 + 2];
    float b3 = wp[(size_t)k * 96 + 3];
    float b4 = wp[(size_t)k * 96 + 4];
    float b5 = wp[(size_t)k * 96 + 5];
    acc[0][0] += av0 * b0; acc[0][1] += av0 * b1; acc[0][2] += av0 * b2;
    acc[0][3] += av0 * b3; acc[0][4] += av0 * b4; acc[0][5] += av0 * b5;
    acc[1][0] += av1 * b0; acc[1][1] += av1 * b1; acc[1][2] += av1 * b2;
    acc[1][3] += av1 * b3; acc[1][4] += av1 * b4; acc[1][5] += av1 * b5;
    acc[2][0] += av2 * b0; acc[2][1] += av2 * b1; acc[2][2] += av2 * b2;
    acc[2][3] += av2 * b3; acc[2][4] += av2 * b4; acc[2][5] += av2 * b5;
    acc[3][0] += av3 * b0; acc[3][1] += av3 * b1; acc[3][2] += av3 * b2;
    acc[3][3] += av3 * b3; acc[3][4] += av3 * b4; acc[3][5] += av3 * b5;
  }

#pragma unroll
  for (int i = 0; i < 4; ++i) {
    int r = row0 + tr * 4 + i;
    if (r < M) {
      float rs = rowscale ? rowscale[r] : 1.f;
#pragma unroll
      for (int j = 0; j < 6; ++j) {
        int c = tc * 6 + j;
        float v = acc[i][j] + (bias ? bias[c] : 0.f);
        if (RELU) v = fmaxf(v, 0.f);
        out[(size_t)r * 96 + c] = v * rs;
      }
    }
  }
}

// ---------------- GCN aggregation ----------------
// hw_s is PRE-SCALED: hw_s[i] = (h@W)[i] * dinv[i].
// out[i] = relu(dinv[i] * (sum_{e in row(i)} hw_s[src_e] + hw_s[i]) + bias)
// One wave per node; lane l owns dims l and l+64 (l<32). 4-way edge unroll for MLP.
__global__ __launch_bounds__(256) void k_agg(const float* __restrict__ hw_s,
                                             const int* __restrict__ rowp,
                                             const int* __restrict__ csr,
                                             const float* __restrict__ dinv,
                                             const float* __restrict__ bias,
                                             float* __restrict__ out, int n) {
  int wave = threadIdx.x >> 6;
  int lane = threadIdx.x & 63;
  int node = blockIdx.x * 4 + wave;
  if (node >= n) return;
  int beg = rowp[node], end = rowp[node + 1];
  float acc0 = 0.f, acc1 = 0.f;
  int e = beg;
  for (; e + 4 <= end; e += 4) {
    int s0 = csr[e], s1 = csr[e + 1], s2 = csr[e + 2], s3 = csr[e + 3];
    const float* r0 = hw_s + (size_t)s0 * HID;
    const float* r1 = hw_s + (size_t)s1 * HID;
    const float* r2 = hw_s + (size_t)s2 * HID;
    const float* r3 = hw_s + (size_t)s3 * HID;
    float v0 = r0[lane], v1 = r1[lane], v2 = r2[lane], v3 = r3[lane];
    float u0 = 0.f, u1 = 0.f, u2 = 0.f, u3 = 0.f;
    if (lane < 32) {
      u0 = r0[64 + lane]; u1 = r1[64 + lane]; u2 = r2[64 + lane]; u3 = r3[64 + lane];
    }
    acc0 += (v0 + v1) + (v2 + v3);
    acc1 += (u0 + u1) + (u2 + u3);
  }
  for (; e < end; ++e) {
    int s = csr[e];
    const float* row = hw_s + (size_t)s * HID;
    acc0 += row[lane];
    if (lane < 32) acc1 += row[64 + lane];
  }
  float di = dinv[node];
  const float* srow = hw_s + (size_t)node * HID;
  float r0v = di * (acc0 + srow[lane]) + bias[lane];
  out[(size_t)node * HID + lane] = fmaxf(r0v, 0.f);
  if (lane < 32) {
    float r1v = di * (acc1 + srow[64 + lane]) + bias[64 + lane];
    out[(size_t)node * HID + 64 + lane] = fmaxf(r1v, 0.f);
  }
}

// ---------------- global add pool (batch sorted) ----------------
__global__ __launch_bounds__(128) void k_pool(const float* __restrict__ h,
                                              const int* __restrict__ batch, int n,
                                              float* __restrict__ g) {
  int gr = blockIdx.x;
  int d = threadIdx.x;
  int lo = 0, hi = n;
  while (lo < hi) { int m = (lo + hi) >> 1; if (batch[m] < gr) lo = m + 1; else hi = m; }
  int start = lo;
  hi = n;
  while (lo < hi) { int m = (lo + hi) >> 1; if (batch[m] < gr + 1) lo = m + 1; else hi = m; }
  int end = lo;
  if (d < HID) {
    float s = 0.f;
    for (int i = start; i < end; ++i) s += h[(size_t)i * HID + d];
    g[gr * HID + d] = s;
  }
}

// ---------------- decoder layer 2 ----------------
__global__ void k_dec2(const float* __restrict__ g2, const float* __restrict__ W,
                       const float* __restrict__ b, float* __restrict__ out, int G) {
  int idx = blockIdx.x * 256 + threadIdx.x;
  if (idx >= G * OUTDIM) return;
  int r = idx / OUTDIM, c = idx % OUTDIM;
  float s = b[c];
  const float* row = g2 + (size_t)r * HID;
  for (int k = 0; k < HID; ++k) s += row[k] * W[k * OUTDIM + c];
  out[idx] = s;
}

extern "C" void kernel_launch(void* const* d_in, const int* in_sizes, int n_in,
                              void* d_out, int out_size, void* d_ws, size_t ws_size,
                              hipStream_t stream) {
  const float* x     = (const float*)d_in[0];
  const int*   ei    = (const int*)d_in[1];
  const int*   batch = (const int*)d_in[2];
  const float* encW0 = (const float*)d_in[3];
  const float* encb0 = (const float*)d_in[4];
  const float* encW1 = (const float*)d_in[5];
  const float* encb1 = (const float*)d_in[6];
  const float* convW = (const float*)d_in[7];
  const float* convb = (const float*)d_in[8];
  const float* decW0 = (const float*)d_in[9];
  const float* decb0 = (const float*)d_in[10];
  const float* decW1 = (const float*)d_in[11];
  const float* decb1 = (const float*)d_in[12];
  float* out = (float*)d_out;

  int n  = in_sizes[0] / INDIM;
  int E  = in_sizes[1] / 2;
  int G  = out_size / OUTDIM;
  int NC = in_sizes[7] / (HID * HID);

  const int* srcI = ei;
  const int* dstI = ei + E;

  char* w = (char*)d_ws;
  auto alloc = [&](size_t bytes) {
    char* p = w;
    w += (bytes + 255) & ~(size_t)255;
    return p;
  };
  float* bufA  = (float*)alloc((size_t)n * HID * 4);
  float* bufB  = (float*)alloc((size_t)n * HID * 4);
  int*   cnt   = (int*)alloc((size_t)n * 4);
  int*   cursor= (int*)alloc((size_t)n * 4);
  int*   rowp  = (int*)alloc((size_t)(n + 1) * 4);
  int*   csr   = (int*)alloc((size_t)E * 4);
  float* dinv  = (float*)alloc((size_t)n * 4);
  int*   bsum  = (int*)alloc(256 * 4);
  int*   boff  = (int*)alloc(256 * 4);
  float* g1    = (float*)alloc((size_t)G * HID * 4);
  float* g2    = (float*)alloc((size_t)G * HID * 4);

  hipMemsetAsync(cnt, 0, (size_t)n * 4, stream);
  hipMemsetAsync(cursor, 0, (size_t)n * 4, stream);

  int eb = (E + 255) / 256;
  int nb = (n + 511) / 512;
  k_count<<<eb, 256, 0, stream>>>(dstI, E, cnt);
  k_dinv<<<(n + 255) / 256, 256, 0, stream>>>(cnt, dinv, n);
  k_scanA<<<nb, 256, 0, stream>>>(cnt, n, bsum);
  k_scanB<<<1, 256, 0, stream>>>(bsum, nb, boff, rowp, n);
  k_scanC<<<nb, 256, 0, stream>>>(cnt, n, boff, rowp);
  k_fill<<<eb, 256, 0, stream>>>(srcI, dstI, E, rowp, cursor, csr);

  int gb = (n + 63) / 64;
  gemm96k<128, true><<<gb, 256, 0, stream>>>(x, encW0, encb0, nullptr, bufA, n);
  gemm96k<96, false><<<gb, 256, 0, stream>>>(bufA, encW1, encb1, nullptr, bufB, n);
  for (int l = 0; l < NC; ++l) {
    // hw_scaled = (h @ W) * dinv[row]
    gemm96k<96, false><<<gb, 256, 0, stream>>>(bufB, convW + (size_t)l * HID * HID,
                                               nullptr, dinv, bufA, n);
    k_agg<<<(n + 3) / 4, 256, 0, stream>>>(bufA, rowp, csr, dinv,
                                           convb + (size_t)l * HID, bufB, n);
  }
  k_pool<<<G, 128, 0, stream>>>(bufB, batch, n, g1);
  gemm96k<96, true><<<(G + 63) / 64, 256, 0, stream>>>(g1, decW0, decb0, nullptr, g2, G);
  k_dec2<<<(G * OUTDIM + 255) / 256, 256, 0, stream>>>(g2, decW1, decb1, out, G);
}

// Round 4
// 558.092 us; speedup vs baseline: 1.4855x; 1.0337x over previous
//
#include <hip/hip_runtime.h>

#define HID 96
#define INDIM 128
#define OUTDIM 10

// ---------------- CSR build ----------------
__global__ void k_count(const int* __restrict__ dst, int E, int* __restrict__ cnt) {
  int i = blockIdx.x * 256 + threadIdx.x;
  if (i < E) atomicAdd(&cnt[dst[i]], 1);
}

__global__ void k_dinv(const int* __restrict__ cnt, float* __restrict__ dinv, int n) {
  int i = blockIdx.x * 256 + threadIdx.x;
  if (i < n) dinv[i] = rsqrtf((float)cnt[i] + 1.0f);
}

// ---- two-level scan
__global__ __launch_bounds__(256) void k_scanA(const int* __restrict__ cnt, int n,
                                               int* __restrict__ bsum) {
  __shared__ int red[256];
  int b = blockIdx.x, t = threadIdx.x;
  int base = b * 512;
  int v = 0;
  int i0 = base + t, i1 = base + 256 + t;
  if (i0 < n) v += cnt[i0];
  if (i1 < n) v += cnt[i1];
  red[t] = v;
  __syncthreads();
  for (int off = 128; off > 0; off >>= 1) {
    if (t < off) red[t] += red[t + off];
    __syncthreads();
  }
  if (t == 0) bsum[b] = red[0];
}

__global__ __launch_bounds__(256) void k_scanB(const int* __restrict__ bsum, int nb,
                                               int* __restrict__ boff,
                                               int* __restrict__ rowp, int n) {
  __shared__ int s[256];
  int t = threadIdx.x;
  int v = (t < nb) ? bsum[t] : 0;
  s[t] = v;
  __syncthreads();
  for (int off = 1; off < 256; off <<= 1) {
    int u = (t >= off) ? s[t - off] : 0;
    __syncthreads();
    s[t] += u;
    __syncthreads();
  }
  if (t < nb) boff[t] = s[t] - v;
  if (t == 255) rowp[n] = s[255];
}

__global__ __launch_bounds__(256) void k_scanC(const int* __restrict__ cnt, int n,
                                               const int* __restrict__ boff,
                                               int* __restrict__ rowp) {
  __shared__ int s[256];
  int b = blockIdx.x, t = threadIdx.x;
  int base = b * 512;
  int i0 = base + 2 * t, i1 = i0 + 1;
  int c0 = (i0 < n) ? cnt[i0] : 0;
  int c1 = (i1 < n) ? cnt[i1] : 0;
  int pair = c0 + c1;
  s[t] = pair;
  __syncthreads();
  for (int off = 1; off < 256; off <<= 1) {
    int u = (t >= off) ? s[t - off] : 0;
    __syncthreads();
    s[t] += u;
    __syncthreads();
  }
  int excl = s[t] - pair + boff[b];
  if (i0 < n) rowp[i0] = excl;
  if (i1 < n) rowp[i1] = excl + c0;
}

__global__ void k_fill(const int* __restrict__ src, const int* __restrict__ dst, int E,
                       const int* __restrict__ rowp, int* __restrict__ cursor,
                       int* __restrict__ csr) {
  int i = blockIdx.x * 256 + threadIdx.x;
  if (i < E) {
    int d = dst[i];
    int pos = atomicAdd(&cursor[d], 1);
    csr[rowp[d] + pos] = src[i];
  }
}

// ---------------- GEMM: out[M x 96] = A[M x K] @ W[K x 96] (+bias)(+relu)(*rowscale) ----
// K-chunked staging (KC=32) keeps LDS at ~21.5 KB -> 6 blocks/CU.
template <int K, bool RELU>
__global__ __launch_bounds__(256, 6) void gemm96k(const float* __restrict__ A,
                                                  const float* __restrict__ W,
                                                  const float* __restrict__ bias,
                                                  const float* __restrict__ rowscale,
                                                  float* __restrict__ out, int M) {
  constexpr int KC = 32;
  constexpr int NCH = K / KC;
  constexpr int APAD = KC + 4;  // 36: A-read banks = (4r + k) mod 32 -> 2-way, free
  __shared__ float wL[KC * 96];
  __shared__ float aL[64 * APAD];

  int t = threadIdx.x;
  int row0 = blockIdx.x * 64;

  int tr = t >> 4;
  int tc = t & 15;
  float acc[4][6];
#pragma unroll
  for (int i = 0; i < 4; ++i)
#pragma unroll
    for (int j = 0; j < 6; ++j) acc[i][j] = 0.f;

  const float* a0p = &aL[(tr * 4 + 0) * APAD];
  const float* a1p = &aL[(tr * 4 + 1) * APAD];
  const float* a2p = &aL[(tr * 4 + 2) * APAD];
  const float* a3p = &aL[(tr * 4 + 3) * APAD];
  const float* wp = &wL[tc * 6];

  for (int ch = 0; ch < NCH; ++ch) {
    // stage W chunk: rows [ch*32, ch*32+32) of W[K][96] -- contiguous 12 KB
    {
      const float4* wg = (const float4*)(W + (size_t)ch * KC * 96);
      float4* wf = (float4*)wL;
#pragma unroll
      for (int i = 0; i < 3; ++i) wf[t + 256 * i] = wg[t + 256 * i];
    }
    // stage A chunk: 64 rows x 32 cols (8 float4 per row)
    {
#pragma unroll
      for (int i = 0; i < 2; ++i) {
        int idx = t + 256 * i;
        int r = idx >> 3, c4 = idx & 7;
        float4 v = make_float4(0.f, 0.f, 0.f, 0.f);
        int gr = row0 + r;
        if (gr < M) v = ((const float4*)(A + (size_t)gr * K + ch * KC))[c4];
        *(float4*)&aL[r * APAD + c4 * 4] = v;
      }
    }
    __syncthreads();

#pragma unroll
    for (int k = 0; k < KC; ++k) {
      float av0 = a0p[k], av1 = a1p[k], av2 = a2p[k], av3 = a3p[k];
      float b0 = wp[k * 96 + 0];
      float b1 = wp[k * 96 + 1];
      float b2 = wp[k * 96 + 2];
      float b3 = wp[k * 96 + 3];
      float b4 = wp[k * 96 + 4];
      float b5 = wp[k * 96 + 5];
      acc[0][0] += av0 * b0; acc[0][1] += av0 * b1; acc[0][2] += av0 * b2;
      acc[0][3] += av0 * b3; acc[0][4] += av0 * b4; acc[0][5] += av0 * b5;
      acc[1][0] += av1 * b0; acc[1][1] += av1 * b1; acc[1][2] += av1 * b2;
      acc[1][3] += av1 * b3; acc[1][4] += av1 * b4; acc[1][5] += av1 * b5;
      acc[2][0] += av2 * b0; acc[2][1] += av2 * b1; acc[2][2] += av2 * b2;
      acc[2][3] += av2 * b3; acc[2][4] += av2 * b4; acc[2][5] += av2 * b5;
      acc[3][0] += av3 * b0; acc[3][1] += av3 * b1; acc[3][2] += av3 * b2;
      acc[3][3] += av3 * b3; acc[3][4] += av3 * b4; acc[3][5] += av3 * b5;
    }
    __syncthreads();
  }

#pragma unroll
  for (int i = 0; i < 4; ++i) {
    int r = row0 + tr * 4 + i;
    if (r < M) {
      float rs = rowscale ? rowscale[r] : 1.f;
#pragma unroll
      for (int j = 0; j < 6; ++j) {
        int c = tc * 6 + j;
        float v = acc[i][j] + (bias ? bias[c] : 0.f);
        if (RELU) v = fmaxf(v, 0.f);
        out[(size_t)r * 96 + c] = v * rs;
      }
    }
  }
}

// ---------------- GCN aggregation ----------------
// hw_s is PRE-SCALED: hw_s[i] = (h@W)[i] * dinv[i].
// out[i] = relu(dinv[i] * (sum_{e in row(i)} hw_s[src_e] + hw_s[i]) + bias)
__global__ __launch_bounds__(256) void k_agg(const float* __restrict__ hw_s,
                                             const int* __restrict__ rowp,
                                             const int* __restrict__ csr,
                                             const float* __restrict__ dinv,
                                             const float* __restrict__ bias,
                                             float* __restrict__ out, int n) {
  int wave = threadIdx.x >> 6;
  int lane = threadIdx.x & 63;
  int node = blockIdx.x * 4 + wave;
  if (node >= n) return;
  int beg = rowp[node], end = rowp[node + 1];
  float acc0 = 0.f, acc1 = 0.f;
  int e = beg;
  for (; e + 4 <= end; e += 4) {
    int s0 = csr[e], s1 = csr[e + 1], s2 = csr[e + 2], s3 = csr[e + 3];
    const float* r0 = hw_s + (size_t)s0 * HID;
    const float* r1 = hw_s + (size_t)s1 * HID;
    const float* r2 = hw_s + (size_t)s2 * HID;
    const float* r3 = hw_s + (size_t)s3 * HID;
    float v0 = r0[lane], v1 = r1[lane], v2 = r2[lane], v3 = r3[lane];
    float u0 = 0.f, u1 = 0.f, u2 = 0.f, u3 = 0.f;
    if (lane < 32) {
      u0 = r0[64 + lane]; u1 = r1[64 + lane]; u2 = r2[64 + lane]; u3 = r3[64 + lane];
    }
    acc0 += (v0 + v1) + (v2 + v3);
    acc1 += (u0 + u1) + (u2 + u3);
  }
  for (; e < end; ++e) {
    int s = csr[e];
    const float* row = hw_s + (size_t)s * HID;
    acc0 += row[lane];
    if (lane < 32) acc1 += row[64 + lane];
  }
  float di = dinv[node];
  const float* srow = hw_s + (size_t)node * HID;
  float r0v = di * (acc0 + srow[lane]) + bias[lane];
  out[(size_t)node * HID + lane] = fmaxf(r0v, 0.f);
  if (lane < 32) {
    float r1v = di * (acc1 + srow[64 + lane]) + bias[64 + lane];
    out[(size_t)node * HID + 64 + lane] = fmaxf(r1v, 0.f);
  }
}

// ---------------- global add pool (batch sorted) ----------------
__global__ __launch_bounds__(128) void k_pool(const float* __restrict__ h,
                                              const int* __restrict__ batch, int n,
                                              float* __restrict__ g) {
  int gr = blockIdx.x;
  int d = threadIdx.x;
  int lo = 0, hi = n;
  while (lo < hi) { int m = (lo + hi) >> 1; if (batch[m] < gr) lo = m + 1; else hi = m; }
  int start = lo;
  hi = n;
  while (lo < hi) { int m = (lo + hi) >> 1; if (batch[m] < gr + 1) lo = m + 1; else hi = m; }
  int end = lo;
  if (d < HID) {
    float s = 0.f;
    for (int i = start; i < end; ++i) s += h[(size_t)i * HID + d];
    g[gr * HID + d] = s;
  }
}

// ---------------- decoder layer 2 ----------------
__global__ void k_dec2(const float* __restrict__ g2, const float* __restrict__ W,
                       const float* __restrict__ b, float* __restrict__ out, int G) {
  int idx = blockIdx.x * 256 + threadIdx.x;
  if (idx >= G * OUTDIM) return;
  int r = idx / OUTDIM, c = idx % OUTDIM;
  float s = b[c];
  const float* row = g2 + (size_t)r * HID;
  for (int k = 0; k < HID; ++k) s += row[k] * W[k * OUTDIM + c];
  out[idx] = s;
}

extern "C" void kernel_launch(void* const* d_in, const int* in_sizes, int n_in,
                              void* d_out, int out_size, void* d_ws, size_t ws_size,
                              hipStream_t stream) {
  const float* x     = (const float*)d_in[0];
  const int*   ei    = (const int*)d_in[1];
  const int*   batch = (const int*)d_in[2];
  const float* encW0 = (const float*)d_in[3];
  const float* encb0 = (const float*)d_in[4];
  const float* encW1 = (const float*)d_in[5];
  const float* encb1 = (const float*)d_in[6];
  const float* convW = (const float*)d_in[7];
  const float* convb = (const float*)d_in[8];
  const float* decW0 = (const float*)d_in[9];
  const float* decb0 = (const float*)d_in[10];
  const float* decW1 = (const float*)d_in[11];
  const float* decb1 = (const float*)d_in[12];
  float* out = (float*)d_out;

  int n  = in_sizes[0] / INDIM;
  int E  = in_sizes[1] / 2;
  int G  = out_size / OUTDIM;
  int NC = in_sizes[7] / (HID * HID);

  const int* srcI = ei;
  const int* dstI = ei + E;

  char* w = (char*)d_ws;
  auto alloc = [&](size_t bytes) {
    char* p = w;
    w += (bytes + 255) & ~(size_t)255;
    return p;
  };
  float* bufA  = (float*)alloc((size_t)n * HID * 4);
  float* bufB  = (float*)alloc((size_t)n * HID * 4);
  int*   cnt   = (int*)alloc((size_t)n * 4);
  int*   cursor= (int*)alloc((size_t)n * 4);
  int*   rowp  = (int*)alloc((size_t)(n + 1) * 4);
  int*   csr   = (int*)alloc((size_t)E * 4);
  float* dinv  = (float*)alloc((size_t)n * 4);
  int*   bsum  = (int*)alloc(256 * 4);
  int*   boff  = (int*)alloc(256 * 4);
  float* g1    = (float*)alloc((size_t)G * HID * 4);
  float* g2    = (float*)alloc((size_t)G * HID * 4);

  hipMemsetAsync(cnt, 0, (size_t)n * 4, stream);
  hipMemsetAsync(cursor, 0, (size_t)n * 4, stream);

  int eb = (E + 255) / 256;
  int nb = (n + 511) / 512;
  k_count<<<eb, 256, 0, stream>>>(dstI, E, cnt);
  k_dinv<<<(n + 255) / 256, 256, 0, stream>>>(cnt, dinv, n);
  k_scanA<<<nb, 256, 0, stream>>>(cnt, n, bsum);
  k_scanB<<<1, 256, 0, stream>>>(bsum, nb, boff, rowp, n);
  k_scanC<<<nb, 256, 0, stream>>>(cnt, n, boff, rowp);
  k_fill<<<eb, 256, 0, stream>>>(srcI, dstI, E, rowp, cursor, csr);

  int gb = (n + 63) / 64;
  gemm96k<128, true><<<gb, 256, 0, stream>>>(x, encW0, encb0, nullptr, bufA, n);
  gemm96k<96, false><<<gb, 256, 0, stream>>>(bufA, encW1, encb1, nullptr, bufB, n);
  for (int l = 0; l < NC; ++l) {
    gemm96k<96, false><<<gb, 256, 0, stream>>>(bufB, convW + (size_t)l * HID * HID,
                                               nullptr, dinv, bufA, n);
    k_agg<<<(n + 3) / 4, 256, 0, stream>>>(bufA, rowp, csr, dinv,
                                           convb + (size_t)l * HID, bufB, n);
  }
  k_pool<<<G, 128, 0, stream>>>(bufB, batch, n, g1);
  gemm96k<96, true><<<(G + 63) / 64, 256, 0, stream>>>(g1, decW0, decb0, nullptr, g2, G);
  k_dec2<<<(G * OUTDIM + 255) / 256, 256, 0, stream>>>(g2, decW1, decb1, out, G);
}

// Round 5
// 414.337 us; speedup vs baseline: 2.0008x; 1.3470x over previous
//
#include <hip/hip_runtime.h>

#define HID 96
#define INDIM 128
#define OUTDIM 10

__device__ __forceinline__ unsigned short f2bf(float f) {
  unsigned int u = __float_as_uint(f);
  unsigned int r = (u + 0x7FFFu + ((u >> 16) & 1u)) >> 16;  // RNE
  return (unsigned short)r;
}

// ---------------- CSR build ----------------
// count + per-edge rank (position within its dst bucket)
__global__ void k_count(const int* __restrict__ dst, int E, int* __restrict__ cnt,
                        int* __restrict__ rank) {
  int base = (blockIdx.x * 256 + threadIdx.x) * 4;
#pragma unroll
  for (int j = 0; j < 4; ++j) {
    int e = base + j;
    if (e < E) rank[e] = atomicAdd(&cnt[dst[e]], 1);
  }
}

// ---- two-level scan (+ dinv fused)
__global__ __launch_bounds__(256) void k_scanA(const int* __restrict__ cnt, int n,
                                               int* __restrict__ bsum,
                                               float* __restrict__ dinv) {
  __shared__ int red[256];
  int b = blockIdx.x, t = threadIdx.x;
  int base = b * 512;
  int v = 0;
  int i0 = base + t, i1 = base + 256 + t;
  if (i0 < n) { int c = cnt[i0]; v += c; dinv[i0] = rsqrtf((float)c + 1.0f); }
  if (i1 < n) { int c = cnt[i1]; v += c; dinv[i1] = rsqrtf((float)c + 1.0f); }
  red[t] = v;
  __syncthreads();
  for (int off = 128; off > 0; off >>= 1) {
    if (t < off) red[t] += red[t + off];
    __syncthreads();
  }
  if (t == 0) bsum[b] = red[0];
}

__global__ __launch_bounds__(256) void k_scanB(const int* __restrict__ bsum, int nb,
                                               int* __restrict__ boff,
                                               int* __restrict__ rowp, int n) {
  __shared__ int s[256];
  int t = threadIdx.x;
  int v = (t < nb) ? bsum[t] : 0;
  s[t] = v;
  __syncthreads();
  for (int off = 1; off < 256; off <<= 1) {
    int u = (t >= off) ? s[t - off] : 0;
    __syncthreads();
    s[t] += u;
    __syncthreads();
  }
  if (t < nb) boff[t] = s[t] - v;
  if (t == 255) rowp[n] = s[255];
}

__global__ __launch_bounds__(256) void k_scanC(const int* __restrict__ cnt, int n,
                                               const int* __restrict__ boff,
                                               int* __restrict__ rowp) {
  __shared__ int s[256];
  int b = blockIdx.x, t = threadIdx.x;
  int base = b * 512;
  int i0 = base + 2 * t, i1 = i0 + 1;
  int c0 = (i0 < n) ? cnt[i0] : 0;
  int c1 = (i1 < n) ? cnt[i1] : 0;
  int pair = c0 + c1;
  s[t] = pair;
  __syncthreads();
  for (int off = 1; off < 256; off <<= 1) {
    int u = (t >= off) ? s[t - off] : 0;
    __syncthreads();
    s[t] += u;
    __syncthreads();
  }
  int excl = s[t] - pair + boff[b];
  if (i0 < n) rowp[i0] = excl;
  if (i1 < n) rowp[i1] = excl + c0;
}

// atomic-free fill using precomputed rank
__global__ void k_fill(const int* __restrict__ src, const int* __restrict__ dst,
                       const int* __restrict__ rank, int E,
                       const int* __restrict__ rowp, int* __restrict__ csr) {
  int base = (blockIdx.x * 256 + threadIdx.x) * 4;
#pragma unroll
  for (int j = 0; j < 4; ++j) {
    int e = base + j;
    if (e < E) csr[rowp[dst[e]] + rank[e]] = src[e];
  }
}

// ---------------- GEMM: out[M x 96] = A[M x K] @ W[K x 96] (+bias)(+relu)(*rowscale) ----
// K-chunked staging (KC=32): ~21.5 KB LDS -> 6 blocks/CU.
// OUT_BF16: write rows as 96 bf16 (48 uints) for the aggregation gather.
template <int K, bool RELU, bool OUT_BF16>
__global__ __launch_bounds__(256, 6) void gemm96k(const float* __restrict__ A,
                                                  const float* __restrict__ W,
                                                  const float* __restrict__ bias,
                                                  const float* __restrict__ rowscale,
                                                  float* __restrict__ out, int M) {
  constexpr int KC = 32;
  constexpr int NCH = K / KC;
  constexpr int APAD = KC + 4;
  __shared__ float wL[KC * 96];
  __shared__ float aL[64 * APAD];

  int t = threadIdx.x;
  int row0 = blockIdx.x * 64;

  int tr = t >> 4;
  int tc = t & 15;
  float acc[4][6];
#pragma unroll
  for (int i = 0; i < 4; ++i)
#pragma unroll
    for (int j = 0; j < 6; ++j) acc[i][j] = 0.f;

  const float* a0p = &aL[(tr * 4 + 0) * APAD];
  const float* a1p = &aL[(tr * 4 + 1) * APAD];
  const float* a2p = &aL[(tr * 4 + 2) * APAD];
  const float* a3p = &aL[(tr * 4 + 3) * APAD];
  const float* wp = &wL[tc * 6];

  for (int ch = 0; ch < NCH; ++ch) {
    {
      const float4* wg = (const float4*)(W + (size_t)ch * KC * 96);
      float4* wf = (float4*)wL;
#pragma unroll
      for (int i = 0; i < 3; ++i) wf[t + 256 * i] = wg[t + 256 * i];
    }
    {
#pragma unroll
      for (int i = 0; i < 2; ++i) {
        int idx = t + 256 * i;
        int r = idx >> 3, c4 = idx & 7;
        float4 v = make_float4(0.f, 0.f, 0.f, 0.f);
        int gr = row0 + r;
        if (gr < M) v = ((const float4*)(A + (size_t)gr * K + ch * KC))[c4];
        *(float4*)&aL[r * APAD + c4 * 4] = v;
      }
    }
    __syncthreads();

#pragma unroll
    for (int k = 0; k < KC; ++k) {
      float av0 = a0p[k], av1 = a1p[k], av2 = a2p[k], av3 = a3p[k];
      float b0 = wp[k * 96 + 0];
      float b1 = wp[k * 96 + 1];
      float b2 = wp[k * 96 + 2];
      float b3 = wp[k * 96 + 3];
      float b4 = wp[k * 96 + 4];
      float b5 = wp[k * 96 + 5];
      acc[0][0] += av0 * b0; acc[0][1] += av0 * b1; acc[0][2] += av0 * b2;
      acc[0][3] += av0 * b3; acc[0][4] += av0 * b4; acc[0][5] += av0 * b5;
      acc[1][0] += av1 * b0; acc[1][1] += av1 * b1; acc[1][2] += av1 * b2;
      acc[1][3] += av1 * b3; acc[1][4] += av1 * b4; acc[1][5] += av1 * b5;
      acc[2][0] += av2 * b0; acc[2][1] += av2 * b1; acc[2][2] += av2 * b2;
      acc[2][3] += av2 * b3; acc[2][4] += av2 * b4; acc[2][5] += av2 * b5;
      acc[3][0] += av3 * b0; acc[3][1] += av3 * b1; acc[3][2] += av3 * b2;
      acc[3][3] += av3 * b3; acc[3][4] += av3 * b4; acc[3][5] += av3 * b5;
    }
    __syncthreads();
  }

#pragma unroll
  for (int i = 0; i < 4; ++i) {
    int r = row0 + tr * 4 + i;
    if (r < M) {
      float rs = rowscale ? rowscale[r] : 1.f;
      float v[6];
#pragma unroll
      for (int j = 0; j < 6; ++j) {
        float u = acc[i][j] + (bias ? bias[tc * 6 + j] : 0.f);
        if (RELU) u = fmaxf(u, 0.f);
        v[j] = u * rs;
      }
      if (OUT_BF16) {
        unsigned int* ob = (unsigned int*)out;  // row stride 48 uints
        unsigned int p0 = (unsigned int)f2bf(v[0]) | ((unsigned int)f2bf(v[1]) << 16);
        unsigned int p1 = (unsigned int)f2bf(v[2]) | ((unsigned int)f2bf(v[3]) << 16);
        unsigned int p2 = (unsigned int)f2bf(v[4]) | ((unsigned int)f2bf(v[5]) << 16);
        ob[(size_t)r * 48 + tc * 3 + 0] = p0;
        ob[(size_t)r * 48 + tc * 3 + 1] = p1;
        ob[(size_t)r * 48 + tc * 3 + 2] = p2;
      } else {
#pragma unroll
        for (int j = 0; j < 6; ++j) out[(size_t)r * 96 + tc * 6 + j] = v[j];
      }
    }
  }
}

// ---------------- GCN aggregation (bf16 gather, f32 accumulate) ----------------
// hw_s rows: 96 bf16 = 48 uints. Lane l<48 owns dims (2l, 2l+1).
// out[i] = relu(dinv[i] * (sum_e hw_s[src_e] + hw_s[i]) + bias)   [hw_s pre-scaled by dinv]
__global__ __launch_bounds__(256) void k_agg(const unsigned int* __restrict__ hw_s,
                                             const int* __restrict__ rowp,
                                             const int* __restrict__ csr,
                                             const float* __restrict__ dinv,
                                             const float* __restrict__ bias,
                                             float* __restrict__ out, int n) {
  int wave = threadIdx.x >> 6;
  int lane = threadIdx.x & 63;
  int node = blockIdx.x * 4 + wave;
  if (node >= n) return;
  int beg = rowp[node], end = rowp[node + 1];
  float acc0 = 0.f, acc1 = 0.f;
  bool act = lane < 48;
  int li = act ? lane : 0;
  int e = beg;
  for (; e + 8 <= end; e += 8) {
    unsigned int u0 = hw_s[(size_t)csr[e + 0] * 48 + li];
    unsigned int u1 = hw_s[(size_t)csr[e + 1] * 48 + li];
    unsigned int u2 = hw_s[(size_t)csr[e + 2] * 48 + li];
    unsigned int u3 = hw_s[(size_t)csr[e + 3] * 48 + li];
    unsigned int u4 = hw_s[(size_t)csr[e + 4] * 48 + li];
    unsigned int u5 = hw_s[(size_t)csr[e + 5] * 48 + li];
    unsigned int u6 = hw_s[(size_t)csr[e + 6] * 48 + li];
    unsigned int u7 = hw_s[(size_t)csr[e + 7] * 48 + li];
    acc0 += __uint_as_float(u0 << 16) + __uint_as_float(u1 << 16) +
            __uint_as_float(u2 << 16) + __uint_as_float(u3 << 16) +
            __uint_as_float(u4 << 16) + __uint_as_float(u5 << 16) +
            __uint_as_float(u6 << 16) + __uint_as_float(u7 << 16);
    acc1 += __uint_as_float(u0 & 0xFFFF0000u) + __uint_as_float(u1 & 0xFFFF0000u) +
            __uint_as_float(u2 & 0xFFFF0000u) + __uint_as_float(u3 & 0xFFFF0000u) +
            __uint_as_float(u4 & 0xFFFF0000u) + __uint_as_float(u5 & 0xFFFF0000u) +
            __uint_as_float(u6 & 0xFFFF0000u) + __uint_as_float(u7 & 0xFFFF0000u);
  }
  for (; e + 4 <= end; e += 4) {
    unsigned int u0 = hw_s[(size_t)csr[e + 0] * 48 + li];
    unsigned int u1 = hw_s[(size_t)csr[e + 1] * 48 + li];
    unsigned int u2 = hw_s[(size_t)csr[e + 2] * 48 + li];
    unsigned int u3 = hw_s[(size_t)csr[e + 3] * 48 + li];
    acc0 += __uint_as_float(u0 << 16) + __uint_as_float(u1 << 16) +
            __uint_as_float(u2 << 16) + __uint_as_float(u3 << 16);
    acc1 += __uint_as_float(u0 & 0xFFFF0000u) + __uint_as_float(u1 & 0xFFFF0000u) +
            __uint_as_float(u2 & 0xFFFF0000u) + __uint_as_float(u3 & 0xFFFF0000u);
  }
  for (; e < end; ++e) {
    unsigned int u = hw_s[(size_t)csr[e] * 48 + li];
    acc0 += __uint_as_float(u << 16);
    acc1 += __uint_as_float(u & 0xFFFF0000u);
  }
  if (act) {
    float di = dinv[node];
    unsigned int us = hw_s[(size_t)node * 48 + li];
    float s0 = __uint_as_float(us << 16);
    float s1 = __uint_as_float(us & 0xFFFF0000u);
    float2 bv = ((const float2*)bias)[li];
    float r0 = di * (acc0 + s0) + bv.x;
    float r1 = di * (acc1 + s1) + bv.y;
    float2 o;
    o.x = fmaxf(r0, 0.f);
    o.y = fmaxf(r1, 0.f);
    ((float2*)(out + (size_t)node * HID))[li] = o;
  }
}

// ---------------- global add pool (batch sorted) ----------------
__global__ __launch_bounds__(128) void k_pool(const float* __restrict__ h,
                                              const int* __restrict__ batch, int n,
                                              float* __restrict__ g) {
  int gr = blockIdx.x;
  int d = threadIdx.x;
  int lo = 0, hi = n;
  while (lo < hi) { int m = (lo + hi) >> 1; if (batch[m] < gr) lo = m + 1; else hi = m; }
  int start = lo;
  hi = n;
  while (lo < hi) { int m = (lo + hi) >> 1; if (batch[m] < gr + 1) lo = m + 1; else hi = m; }
  int end = lo;
  if (d < HID) {
    float s = 0.f;
    for (int i = start; i < end; ++i) s += h[(size_t)i * HID + d];
    g[gr * HID + d] = s;
  }
}

// ---------------- decoder layer 2 ----------------
__global__ void k_dec2(const float* __restrict__ g2, const float* __restrict__ W,
                       const float* __restrict__ b, float* __restrict__ out, int G) {
  int idx = blockIdx.x * 256 + threadIdx.x;
  if (idx >= G * OUTDIM) return;
  int r = idx / OUTDIM, c = idx % OUTDIM;
  float s = b[c];
  const float* row = g2 + (size_t)r * HID;
  for (int k = 0; k < HID; ++k) s += row[k] * W[k * OUTDIM + c];
  out[idx] = s;
}

extern "C" void kernel_launch(void* const* d_in, const int* in_sizes, int n_in,
                              void* d_out, int out_size, void* d_ws, size_t ws_size,
                              hipStream_t stream) {
  const float* x     = (const float*)d_in[0];
  const int*   ei    = (const int*)d_in[1];
  const int*   batch = (const int*)d_in[2];
  const float* encW0 = (const float*)d_in[3];
  const float* encb0 = (const float*)d_in[4];
  const float* encW1 = (const float*)d_in[5];
  const float* encb1 = (const float*)d_in[6];
  const float* convW = (const float*)d_in[7];
  const float* convb = (const float*)d_in[8];
  const float* decW0 = (const float*)d_in[9];
  const float* decb0 = (const float*)d_in[10];
  const float* decW1 = (const float*)d_in[11];
  const float* decb1 = (const float*)d_in[12];
  float* out = (float*)d_out;

  int n  = in_sizes[0] / INDIM;
  int E  = in_sizes[1] / 2;
  int G  = out_size / OUTDIM;
  int NC = in_sizes[7] / (HID * HID);

  const int* srcI = ei;
  const int* dstI = ei + E;

  char* w = (char*)d_ws;
  auto alloc = [&](size_t bytes) {
    char* p = w;
    w += (bytes + 255) & ~(size_t)255;
    return p;
  };
  float* bufA  = (float*)alloc((size_t)n * HID * 4);
  float* bufB  = (float*)alloc((size_t)n * HID * 4);
  unsigned int* hwb = (unsigned int*)alloc((size_t)n * 48 * 4);  // bf16 rows
  int*   cnt   = (int*)alloc((size_t)n * 4);
  int*   rankb = (int*)alloc((size_t)E * 4);
  int*   rowp  = (int*)alloc((size_t)(n + 1) * 4);
  int*   csr   = (int*)alloc((size_t)E * 4);
  float* dinv  = (float*)alloc((size_t)n * 4);
  int*   bsum  = (int*)alloc(256 * 4);
  int*   boff  = (int*)alloc(256 * 4);
  float* g1    = (float*)alloc((size_t)G * HID * 4);
  float* g2    = (float*)alloc((size_t)G * HID * 4);

  hipMemsetAsync(cnt, 0, (size_t)n * 4, stream);

  int eb4 = (E + 1023) / 1024;
  int nb = (n + 511) / 512;
  k_count<<<eb4, 256, 0, stream>>>(dstI, E, cnt, rankb);
  k_scanA<<<nb, 256, 0, stream>>>(cnt, n, bsum, dinv);
  k_scanB<<<1, 256, 0, stream>>>(bsum, nb, boff, rowp, n);
  k_scanC<<<nb, 256, 0, stream>>>(cnt, n, boff, rowp);
  k_fill<<<eb4, 256, 0, stream>>>(srcI, dstI, rankb, E, rowp, csr);

  int gb = (n + 63) / 64;
  gemm96k<128, true, false><<<gb, 256, 0, stream>>>(x, encW0, encb0, nullptr, bufA, n);
  gemm96k<96, false, false><<<gb, 256, 0, stream>>>(bufA, encW1, encb1, nullptr, bufB, n);
  for (int l = 0; l < NC; ++l) {
    // hwb = bf16((h @ W) * dinv[row])
    gemm96k<96, false, true><<<gb, 256, 0, stream>>>(bufB, convW + (size_t)l * HID * HID,
                                                     nullptr, dinv, (float*)hwb, n);
    k_agg<<<(n + 3) / 4, 256, 0, stream>>>(hwb, rowp, csr, dinv,
                                           convb + (size_t)l * HID, bufB, n);
  }
  k_pool<<<G, 128, 0, stream>>>(bufB, batch, n, g1);
  gemm96k<96, true, false><<<(G + 63) / 64, 256, 0, stream>>>(g1, decW0, decb0, nullptr, g2, G);
  k_dec2<<<(G * OUTDIM + 255) / 256, 256, 0, stream>>>(g2, decW1, decb1, out, G);
}

// Round 6
// 321.828 us; speedup vs baseline: 2.5760x; 1.2875x over previous
//
#include <hip/hip_runtime.h>

#define HID 96
#define INDIM 128
#define OUTDIM 10

typedef __attribute__((ext_vector_type(8))) short bf16x8;
typedef __attribute__((ext_vector_type(4))) float f32x4;

__device__ __forceinline__ unsigned short f2bf(float f) {
  unsigned int u = __float_as_uint(f);
  unsigned int r = (u + 0x7FFFu + ((u >> 16) & 1u)) >> 16;  // RNE
  return (unsigned short)r;
}
__device__ __forceinline__ bf16x8 as_bf16x8(uint4 u) {
  union { uint4 a; bf16x8 b; } c; c.a = u; return c.b;
}
__device__ __forceinline__ float bflo(unsigned int u) { return __uint_as_float(u << 16); }
__device__ __forceinline__ float bfhi(unsigned int u) { return __uint_as_float(u & 0xFFFF0000u); }

// ---------------- CSR build ----------------
__global__ void k_count(const int* __restrict__ dst, int E, int* __restrict__ cnt,
                        int* __restrict__ rank) {
  int base = (blockIdx.x * 256 + threadIdx.x) * 4;
#pragma unroll
  for (int j = 0; j < 4; ++j) {
    int e = base + j;
    if (e < E) rank[e] = atomicAdd(&cnt[dst[e]], 1);
  }
}

__global__ __launch_bounds__(256) void k_scanA(const int* __restrict__ cnt, int n,
                                               int* __restrict__ bsum,
                                               float* __restrict__ dinv) {
  __shared__ int red[256];
  int b = blockIdx.x, t = threadIdx.x;
  int base = b * 512;
  int v = 0;
  int i0 = base + t, i1 = base + 256 + t;
  if (i0 < n) { int c = cnt[i0]; v += c; dinv[i0] = rsqrtf((float)c + 1.0f); }
  if (i1 < n) { int c = cnt[i1]; v += c; dinv[i1] = rsqrtf((float)c + 1.0f); }
  red[t] = v;
  __syncthreads();
  for (int off = 128; off > 0; off >>= 1) {
    if (t < off) red[t] += red[t + off];
    __syncthreads();
  }
  if (t == 0) bsum[b] = red[0];
}

__global__ __launch_bounds__(256) void k_scanB(const int* __restrict__ bsum, int nb,
                                               int* __restrict__ boff,
                                               int* __restrict__ rowp, int n) {
  __shared__ int s[256];
  int t = threadIdx.x;
  int v = (t < nb) ? bsum[t] : 0;
  s[t] = v;
  __syncthreads();
  for (int off = 1; off < 256; off <<= 1) {
    int u = (t >= off) ? s[t - off] : 0;
    __syncthreads();
    s[t] += u;
    __syncthreads();
  }
  if (t < nb) boff[t] = s[t] - v;
  if (t == 255) rowp[n] = s[255];
}

__global__ __launch_bounds__(256) void k_scanC(const int* __restrict__ cnt, int n,
                                               const int* __restrict__ boff,
                                               int* __restrict__ rowp) {
  __shared__ int s[256];
  int b = blockIdx.x, t = threadIdx.x;
  int base = b * 512;
  int i0 = base + 2 * t, i1 = i0 + 1;
  int c0 = (i0 < n) ? cnt[i0] : 0;
  int c1 = (i1 < n) ? cnt[i1] : 0;
  int pair = c0 + c1;
  s[t] = pair;
  __syncthreads();
  for (int off = 1; off < 256; off <<= 1) {
    int u = (t >= off) ? s[t - off] : 0;
    __syncthreads();
    s[t] += u;
    __syncthreads();
  }
  int excl = s[t] - pair + boff[b];
  if (i0 < n) rowp[i0] = excl;
  if (i1 < n) rowp[i1] = excl + c0;
}

__global__ void k_fill(const int* __restrict__ src, const int* __restrict__ dst,
                       const int* __restrict__ rank, int E,
                       const int* __restrict__ rowp, int* __restrict__ csr) {
  int base = (blockIdx.x * 256 + threadIdx.x) * 4;
#pragma unroll
  for (int j = 0; j < 4; ++j) {
    int e = base + j;
    if (e < E) csr[rowp[dst[e]] + rank[e]] = src[e];
  }
}

// ---------------- x -> bf16 packed prepass ----------------
__global__ void k_xprep(const float* __restrict__ x, unsigned int* __restrict__ xb,
                        long long nu) {
  long long i = (long long)blockIdx.x * 256 + threadIdx.x;
  if (i < nu) {
    float2 v = ((const float2*)x)[i];
    xb[i] = (unsigned int)f2bf(v.x) | ((unsigned int)f2bf(v.y) << 16);
  }
}

// ---------------- weight -> MFMA B-fragment layout prepass ----------------
// Each block (64 threads) handles one fragment (matrix, ks, cf).
// B-frag: lane l holds B[ks*32 + (l>>4)*8 + j][cf*16 + (l&15)], j=0..7, packed pairs.
__global__ __launch_bounds__(64) void k_wprep(const float* __restrict__ encW0,
                                              const float* __restrict__ encW1,
                                              const float* __restrict__ convW,
                                              uint4* __restrict__ wp, int NC) {
  int bid = blockIdx.x, lane = threadIdx.x;
  const float* Wsrc;
  int frag;
  if (bid < 24) { Wsrc = encW0; frag = bid; }                    // K=128: 4 ks * 6 cf
  else if (bid < 42) { Wsrc = encW1; frag = bid - 24; }          // K=96: 3 * 6
  else { int b = bid - 42; Wsrc = convW + (size_t)(b / 18) * HID * HID; frag = b % 18; }
  int ks = frag / 6, cf = frag % 6;
  int col = cf * 16 + (lane & 15);
  int k0 = ks * 32 + (lane >> 4) * 8;
  unsigned int u[4];
#pragma unroll
  for (int p = 0; p < 4; ++p) {
    float lo = Wsrc[(size_t)(k0 + 2 * p) * 96 + col];
    float hi = Wsrc[(size_t)(k0 + 2 * p + 1) * 96 + col];
    u[p] = (unsigned int)f2bf(lo) | ((unsigned int)f2bf(hi) << 16);
  }
  uint4 r; r.x = u[0]; r.y = u[1]; r.z = u[2]; r.w = u[3];
  wp[(size_t)bid * 64 + lane] = r;
}

// ---------------- MFMA GEMM: out[M x 96] = A[M x K] @ W[K x 96] ----------------
// A: bf16-packed rows (K/2 uints). B: prepped fragments. Out: bf16-packed rows (48 uints).
// Block: 256 thr = 4 waves, each wave 16 rows via mfma_f32_16x16x32_bf16. No LDS.
template <int KS, bool RELU, bool BIAS, bool SCALE>
__global__ __launch_bounds__(256) void mfma_gemm(const uint4* __restrict__ Ab,
                                                 const uint4* __restrict__ Bp,
                                                 const float* __restrict__ bias,
                                                 const float* __restrict__ rowscale,
                                                 unsigned int* __restrict__ outB, int M) {
  int t = threadIdx.x, wid = t >> 6, lane = t & 63;
  int rowbase = blockIdx.x * 64 + wid * 16;
  int arow = rowbase + (lane & 15);
  if (arow >= M) arow = M - 1;
  constexpr int RU4 = KS * 4;  // uint4 per A row

  f32x4 acc[6];
#pragma unroll
  for (int cf = 0; cf < 6; ++cf)
#pragma unroll
    for (int j = 0; j < 4; ++j) acc[cf][j] = 0.f;

#pragma unroll
  for (int ks = 0; ks < KS; ++ks) {
    uint4 a = Ab[(size_t)arow * RU4 + ks * 4 + (lane >> 4)];
    bf16x8 af = as_bf16x8(a);
#pragma unroll
    for (int cf = 0; cf < 6; ++cf) {
      uint4 b = Bp[(size_t)(ks * 6 + cf) * 64 + lane];
      acc[cf] = __builtin_amdgcn_mfma_f32_16x16x32_bf16(af, as_bf16x8(b), acc[cf], 0, 0, 0);
    }
  }

  // epilogue: C/D lane l holds col = cf*16+(l&15), rows rowbase+(l>>4)*4+i
  int rows[4]; float rs[4];
#pragma unroll
  for (int i = 0; i < 4; ++i) {
    rows[i] = rowbase + (lane >> 4) * 4 + i;
    int cr = rows[i] < M ? rows[i] : M - 1;
    rs[i] = SCALE ? rowscale[cr] : 1.f;
  }
#pragma unroll
  for (int cf = 0; cf < 6; ++cf) {
    int col = cf * 16 + (lane & 15);
    float bv = BIAS ? bias[col] : 0.f;
#pragma unroll
    for (int i = 0; i < 4; ++i) {
      float v = acc[cf][i] + bv;
      if (RELU) v = fmaxf(v, 0.f);
      v *= rs[i];
      float p = __shfl_xor(v, 1);
      if (!(lane & 1) && rows[i] < M) {
        unsigned int u = (unsigned int)f2bf(v) | ((unsigned int)f2bf(p) << 16);
        outB[(size_t)rows[i] * 48 + cf * 8 + ((lane & 15) >> 1)] = u;
      }
    }
  }
}

// ---------------- GCN aggregation (bf16 gather, f32 accumulate, bf16 out) ----------------
__global__ __launch_bounds__(256) void k_agg(const unsigned int* __restrict__ hw_s,
                                             const int* __restrict__ rowp,
                                             const int* __restrict__ csr,
                                             const float* __restrict__ dinv,
                                             const float* __restrict__ bias,
                                             unsigned int* __restrict__ outB, int n) {
  int wave = threadIdx.x >> 6;
  int lane = threadIdx.x & 63;
  int node = blockIdx.x * 4 + wave;
  if (node >= n) return;
  int beg = rowp[node], end = rowp[node + 1];
  float acc0 = 0.f, acc1 = 0.f;
  bool act = lane < 48;
  int li = act ? lane : 0;
  int e = beg;
  for (; e + 8 <= end; e += 8) {
    unsigned int u0 = hw_s[(size_t)csr[e + 0] * 48 + li];
    unsigned int u1 = hw_s[(size_t)csr[e + 1] * 48 + li];
    unsigned int u2 = hw_s[(size_t)csr[e + 2] * 48 + li];
    unsigned int u3 = hw_s[(size_t)csr[e + 3] * 48 + li];
    unsigned int u4 = hw_s[(size_t)csr[e + 4] * 48 + li];
    unsigned int u5 = hw_s[(size_t)csr[e + 5] * 48 + li];
    unsigned int u6 = hw_s[(size_t)csr[e + 6] * 48 + li];
    unsigned int u7 = hw_s[(size_t)csr[e + 7] * 48 + li];
    acc0 += bflo(u0) + bflo(u1) + bflo(u2) + bflo(u3) +
            bflo(u4) + bflo(u5) + bflo(u6) + bflo(u7);
    acc1 += bfhi(u0) + bfhi(u1) + bfhi(u2) + bfhi(u3) +
            bfhi(u4) + bfhi(u5) + bfhi(u6) + bfhi(u7);
  }
  for (; e + 4 <= end; e += 4) {
    unsigned int u0 = hw_s[(size_t)csr[e + 0] * 48 + li];
    unsigned int u1 = hw_s[(size_t)csr[e + 1] * 48 + li];
    unsigned int u2 = hw_s[(size_t)csr[e + 2] * 48 + li];
    unsigned int u3 = hw_s[(size_t)csr[e + 3] * 48 + li];
    acc0 += bflo(u0) + bflo(u1) + bflo(u2) + bflo(u3);
    acc1 += bfhi(u0) + bfhi(u1) + bfhi(u2) + bfhi(u3);
  }
  for (; e < end; ++e) {
    unsigned int u = hw_s[(size_t)csr[e] * 48 + li];
    acc0 += bflo(u);
    acc1 += bfhi(u);
  }
  if (act) {
    float di = dinv[node];
    unsigned int us = hw_s[(size_t)node * 48 + li];
    float2 bv = ((const float2*)bias)[li];
    float r0 = fmaxf(di * (acc0 + bflo(us)) + bv.x, 0.f);
    float r1 = fmaxf(di * (acc1 + bfhi(us)) + bv.y, 0.f);
    outB[(size_t)node * 48 + li] = (unsigned int)f2bf(r0) | ((unsigned int)f2bf(r1) << 16);
  }
}

// ---------------- global add pool (bf16 in, f32 out; batch sorted) ----------------
__global__ __launch_bounds__(64) void k_pool(const unsigned int* __restrict__ hb,
                                             const int* __restrict__ batch, int n,
                                             float* __restrict__ g) {
  int gr = blockIdx.x;
  int t = threadIdx.x;
  int lo = 0, hi = n;
  while (lo < hi) { int m = (lo + hi) >> 1; if (batch[m] < gr) lo = m + 1; else hi = m; }
  int start = lo;
  hi = n;
  while (lo < hi) { int m = (lo + hi) >> 1; if (batch[m] < gr + 1) lo = m + 1; else hi = m; }
  int end = lo;
  if (t < 48) {
    float s0 = 0.f, s1 = 0.f;
    for (int i = start; i < end; ++i) {
      unsigned int u = hb[(size_t)i * 48 + t];
      s0 += bflo(u);
      s1 += bfhi(u);
    }
    g[gr * HID + 2 * t] = s0;
    g[gr * HID + 2 * t + 1] = s1;
  }
}

// ---------------- decoder layer 1 (f32 VALU GEMM, M=512) ----------------
__global__ __launch_bounds__(256) void gemm_dec(const float* __restrict__ A,
                                                const float* __restrict__ W,
                                                const float* __restrict__ bias,
                                                float* __restrict__ out, int M) {
  constexpr int KC = 32;
  constexpr int APAD = KC + 4;
  __shared__ float wL[KC * 96];
  __shared__ float aL[64 * APAD];
  int t = threadIdx.x;
  int row0 = blockIdx.x * 64;
  int tr = t >> 4, tc = t & 15;
  float acc[4][6];
#pragma unroll
  for (int i = 0; i < 4; ++i)
#pragma unroll
    for (int j = 0; j < 6; ++j) acc[i][j] = 0.f;
  const float* a0p = &aL[(tr * 4 + 0) * APAD];
  const float* a1p = &aL[(tr * 4 + 1) * APAD];
  const float* a2p = &aL[(tr * 4 + 2) * APAD];
  const float* a3p = &aL[(tr * 4 + 3) * APAD];
  const float* wp = &wL[tc * 6];
  for (int ch = 0; ch < 3; ++ch) {
    {
      const float4* wg = (const float4*)(W + (size_t)ch * KC * 96);
      float4* wf = (float4*)wL;
#pragma unroll
      for (int i = 0; i < 3; ++i) wf[t + 256 * i] = wg[t + 256 * i];
    }
    {
#pragma unroll
      for (int i = 0; i < 2; ++i) {
        int idx = t + 256 * i;
        int r = idx >> 3, c4 = idx & 7;
        float4 v = make_float4(0.f, 0.f, 0.f, 0.f);
        int gr = row0 + r;
        if (gr < M) v = ((const float4*)(A + (size_t)gr * 96 + ch * KC))[c4];
        *(float4*)&aL[r * APAD + c4 * 4] = v;
      }
    }
    __syncthreads();
#pragma unroll
    for (int k = 0; k < KC; ++k) {
      float av0 = a0p[k], av1 = a1p[k], av2 = a2p[k], av3 = a3p[k];
      float b0 = wp[k * 96 + 0], b1 = wp[k * 96 + 1], b2 = wp[k * 96 + 2];
      float b3 = wp[k * 96 + 3], b4 = wp[k * 96 + 4], b5 = wp[k * 96 + 5];
      acc[0][0] += av0 * b0; acc[0][1] += av0 * b1; acc[0][2] += av0 * b2;
      acc[0][3] += av0 * b3; acc[0][4] += av0 * b4; acc[0][5] += av0 * b5;
      acc[1][0] += av1 * b0; acc[1][1] += av1 * b1; acc[1][2] += av1 * b2;
      acc[1][3] += av1 * b3; acc[1][4] += av1 * b4; acc[1][5] += av1 * b5;
      acc[2][0] += av2 * b0; acc[2][1] += av2 * b1; acc[2][2] += av2 * b2;
      acc[2][3] += av2 * b3; acc[2][4] += av2 * b4; acc[2][5] += av2 * b5;
      acc[3][0] += av3 * b0; acc[3][1] += av3 * b1; acc[3][2] += av3 * b2;
      acc[3][3] += av3 * b3; acc[3][4] += av3 * b4; acc[3][5] += av3 * b5;
    }
    __syncthreads();
  }
#pragma unroll
  for (int i = 0; i < 4; ++i) {
    int r = row0 + tr * 4 + i;
    if (r < M) {
#pragma unroll
      for (int j = 0; j < 6; ++j) {
        int c = tc * 6 + j;
        out[(size_t)r * 96 + c] = fmaxf(acc[i][j] + bias[c], 0.f);
      }
    }
  }
}

// ---------------- decoder layer 2 ----------------
__global__ void k_dec2(const float* __restrict__ g2, const float* __restrict__ W,
                       const float* __restrict__ b, float* __restrict__ out, int G) {
  int idx = blockIdx.x * 256 + threadIdx.x;
  if (idx >= G * OUTDIM) return;
  int r = idx / OUTDIM, c = idx % OUTDIM;
  float s = b[c];
  const float* row = g2 + (size_t)r * HID;
  for (int k = 0; k < HID; ++k) s += row[k] * W[k * OUTDIM + c];
  out[idx] = s;
}

extern "C" void kernel_launch(void* const* d_in, const int* in_sizes, int n_in,
                              void* d_out, int out_size, void* d_ws, size_t ws_size,
                              hipStream_t stream) {
  const float* x     = (const float*)d_in[0];
  const int*   ei    = (const int*)d_in[1];
  const int*   batch = (const int*)d_in[2];
  const float* encW0 = (const float*)d_in[3];
  const float* encb0 = (const float*)d_in[4];
  const float* encW1 = (const float*)d_in[5];
  const float* encb1 = (const float*)d_in[6];
  const float* convW = (const float*)d_in[7];
  const float* convb = (const float*)d_in[8];
  const float* decW0 = (const float*)d_in[9];
  const float* decb0 = (const float*)d_in[10];
  const float* decW1 = (const float*)d_in[11];
  const float* decb1 = (const float*)d_in[12];
  float* out = (float*)d_out;

  int n  = in_sizes[0] / INDIM;
  int E  = in_sizes[1] / 2;
  int G  = out_size / OUTDIM;
  int NC = in_sizes[7] / (HID * HID);

  const int* srcI = ei;
  const int* dstI = ei + E;

  char* w = (char*)d_ws;
  auto alloc = [&](size_t bytes) {
    char* p = w;
    w += (bytes + 255) & ~(size_t)255;
    return p;
  };
  unsigned int* xb  = (unsigned int*)alloc((size_t)n * (INDIM / 2) * 4);
  unsigned int* hbA = (unsigned int*)alloc((size_t)n * 48 * 4);
  unsigned int* hbB = (unsigned int*)alloc((size_t)n * 48 * 4);
  unsigned int* hwb = (unsigned int*)alloc((size_t)n * 48 * 4);
  uint4* wp   = (uint4*)alloc((size_t)(42 + NC * 18) * 64 * 16);
  int*   cnt   = (int*)alloc((size_t)n * 4);
  int*   rankb = (int*)alloc((size_t)E * 4);
  int*   rowp  = (int*)alloc((size_t)(n + 1) * 4);
  int*   csr   = (int*)alloc((size_t)E * 4);
  float* dinv  = (float*)alloc((size_t)n * 4);
  int*   bsum  = (int*)alloc(256 * 4);
  int*   boff  = (int*)alloc(256 * 4);
  float* g1    = (float*)alloc((size_t)G * HID * 4);
  float* g2    = (float*)alloc((size_t)G * HID * 4);

  hipMemsetAsync(cnt, 0, (size_t)n * 4, stream);

  int eb4 = (E + 1023) / 1024;
  int nb = (n + 511) / 512;
  k_count<<<eb4, 256, 0, stream>>>(dstI, E, cnt, rankb);
  k_scanA<<<nb, 256, 0, stream>>>(cnt, n, bsum, dinv);
  k_scanB<<<1, 256, 0, stream>>>(bsum, nb, boff, rowp, n);
  k_scanC<<<nb, 256, 0, stream>>>(cnt, n, boff, rowp);
  k_fill<<<eb4, 256, 0, stream>>>(srcI, dstI, rankb, E, rowp, csr);

  long long xu = (long long)n * (INDIM / 2);
  k_xprep<<<(int)((xu + 255) / 256), 256, 0, stream>>>(x, xb, xu);
  k_wprep<<<42 + NC * 18, 64, 0, stream>>>(encW0, encW1, convW, wp, NC);

  int gb = (n + 63) / 64;
  // encoder: enc1 (K=128, relu+bias), enc2 (K=96, bias)
  mfma_gemm<4, true, true, false><<<gb, 256, 0, stream>>>(
      (const uint4*)xb, wp, encb0, nullptr, hbA, n);
  mfma_gemm<3, false, true, false><<<gb, 256, 0, stream>>>(
      (const uint4*)hbA, wp + (size_t)24 * 64, encb1, nullptr, hbB, n);
  for (int l = 0; l < NC; ++l) {
    mfma_gemm<3, false, false, true><<<gb, 256, 0, stream>>>(
        (const uint4*)hbB, wp + (size_t)(42 + l * 18) * 64, nullptr, dinv, hwb, n);
    k_agg<<<(n + 3) / 4, 256, 0, stream>>>(hwb, rowp, csr, dinv,
                                           convb + (size_t)l * HID, hbB, n);
  }
  k_pool<<<G, 64, 0, stream>>>(hbB, batch, n, g1);
  gemm_dec<<<(G + 63) / 64, 256, 0, stream>>>(g1, decW0, decb0, g2, G);
  k_dec2<<<(G * OUTDIM + 255) / 256, 256, 0, stream>>>(g2, decW1, decb1, out, G);
}

// Round 7
// 297.274 us; speedup vs baseline: 2.7887x; 1.0826x over previous
//
#include <hip/hip_runtime.h>

#define HID 96
#define INDIM 128
#define OUTDIM 10

typedef __attribute__((ext_vector_type(8))) short bf16x8;
typedef __attribute__((ext_vector_type(4))) float f32x4;

__device__ __forceinline__ unsigned short f2bf(float f) {
  unsigned int u = __float_as_uint(f);
  unsigned int r = (u + 0x7FFFu + ((u >> 16) & 1u)) >> 16;  // RNE
  return (unsigned short)r;
}
__device__ __forceinline__ bf16x8 as_bf16x8(uint4 u) {
  union { uint4 a; bf16x8 b; } c; c.a = u; return c.b;
}
__device__ __forceinline__ float bflo(unsigned int u) { return __uint_as_float(u << 16); }
__device__ __forceinline__ float bfhi(unsigned int u) { return __uint_as_float(u & 0xFFFF0000u); }

// ---------------- CSR build ----------------
__global__ void k_count(const int4* __restrict__ dst4, int E4, int* __restrict__ cnt,
                        int* __restrict__ rank) {
  int i = blockIdx.x * 256 + threadIdx.x;
  if (i >= E4) return;
  int4 d = dst4[i];
  int r0 = atomicAdd(&cnt[d.x], 1);
  int r1 = atomicAdd(&cnt[d.y], 1);
  int r2 = atomicAdd(&cnt[d.z], 1);
  int r3 = atomicAdd(&cnt[d.w], 1);
  ((int4*)rank)[i] = make_int4(r0, r1, r2, r3);
}

__global__ __launch_bounds__(256) void k_scanA(const int* __restrict__ cnt, int n,
                                               int* __restrict__ bsum,
                                               float* __restrict__ dinv) {
  __shared__ int red[256];
  int b = blockIdx.x, t = threadIdx.x;
  int base = b * 512;
  int v = 0;
  int i0 = base + t, i1 = base + 256 + t;
  if (i0 < n) { int c = cnt[i0]; v += c; dinv[i0] = rsqrtf((float)c + 1.0f); }
  if (i1 < n) { int c = cnt[i1]; v += c; dinv[i1] = rsqrtf((float)c + 1.0f); }
  red[t] = v;
  __syncthreads();
  for (int off = 128; off > 0; off >>= 1) {
    if (t < off) red[t] += red[t + off];
    __syncthreads();
  }
  if (t == 0) bsum[b] = red[0];
}

__global__ __launch_bounds__(256) void k_scanB(const int* __restrict__ bsum, int nb,
                                               int* __restrict__ boff,
                                               int* __restrict__ rowp, int n) {
  __shared__ int s[256];
  int t = threadIdx.x;
  int v = (t < nb) ? bsum[t] : 0;
  s[t] = v;
  __syncthreads();
  for (int off = 1; off < 256; off <<= 1) {
    int u = (t >= off) ? s[t - off] : 0;
    __syncthreads();
    s[t] += u;
    __syncthreads();
  }
  if (t < nb) boff[t] = s[t] - v;
  if (t == 255) rowp[n] = s[255];
}

__global__ __launch_bounds__(256) void k_scanC(const int* __restrict__ cnt, int n,
                                               const int* __restrict__ boff,
                                               int* __restrict__ rowp) {
  __shared__ int s[256];
  int b = blockIdx.x, t = threadIdx.x;
  int base = b * 512;
  int i0 = base + 2 * t, i1 = i0 + 1;
  int c0 = (i0 < n) ? cnt[i0] : 0;
  int c1 = (i1 < n) ? cnt[i1] : 0;
  int pair = c0 + c1;
  s[t] = pair;
  __syncthreads();
  for (int off = 1; off < 256; off <<= 1) {
    int u = (t >= off) ? s[t - off] : 0;
    __syncthreads();
    s[t] += u;
    __syncthreads();
  }
  int excl = s[t] - pair + boff[b];
  if (i0 < n) rowp[i0] = excl;
  if (i1 < n) rowp[i1] = excl + c0;
}

__global__ void k_fill(const int4* __restrict__ src4, const int4* __restrict__ dst4,
                       const int4* __restrict__ rank4, int E4,
                       const int* __restrict__ rowp, int* __restrict__ csr) {
  int i = blockIdx.x * 256 + threadIdx.x;
  if (i >= E4) return;
  int4 s = src4[i];
  int4 d = dst4[i];
  int4 r = rank4[i];
  csr[rowp[d.x] + r.x] = s.x;
  csr[rowp[d.y] + r.y] = s.y;
  csr[rowp[d.z] + r.z] = s.z;
  csr[rowp[d.w] + r.w] = s.w;
}

// ---------------- x -> bf16 packed prepass ----------------
__global__ void k_xprep(const float* __restrict__ x, unsigned int* __restrict__ xb,
                        long long nu) {
  long long i = (long long)blockIdx.x * 256 + threadIdx.x;
  if (i < nu) {
    float2 v = ((const float2*)x)[i];
    xb[i] = (unsigned int)f2bf(v.x) | ((unsigned int)f2bf(v.y) << 16);
  }
}

// ---------------- weight -> MFMA B-fragment layout prepass ----------------
__global__ __launch_bounds__(64) void k_wprep(const float* __restrict__ encW0,
                                              const float* __restrict__ encW1,
                                              const float* __restrict__ convW,
                                              uint4* __restrict__ wp, int NC) {
  int bid = blockIdx.x, lane = threadIdx.x;
  const float* Wsrc;
  int frag;
  if (bid < 24) { Wsrc = encW0; frag = bid; }                    // K=128: 4 ks * 6 cf
  else if (bid < 42) { Wsrc = encW1; frag = bid - 24; }          // K=96: 3 * 6
  else { int b = bid - 42; Wsrc = convW + (size_t)(b / 18) * HID * HID; frag = b % 18; }
  int ks = frag / 6, cf = frag % 6;
  int col = cf * 16 + (lane & 15);
  int k0 = ks * 32 + (lane >> 4) * 8;
  unsigned int u[4];
#pragma unroll
  for (int p = 0; p < 4; ++p) {
    float lo = Wsrc[(size_t)(k0 + 2 * p) * 96 + col];
    float hi = Wsrc[(size_t)(k0 + 2 * p + 1) * 96 + col];
    u[p] = (unsigned int)f2bf(lo) | ((unsigned int)f2bf(hi) << 16);
  }
  uint4 r; r.x = u[0]; r.y = u[1]; r.z = u[2]; r.w = u[3];
  wp[(size_t)bid * 64 + lane] = r;
}

// ---------------- MFMA GEMM ----------------
template <int KS, bool RELU, bool BIAS, bool SCALE>
__global__ __launch_bounds__(256) void mfma_gemm(const uint4* __restrict__ Ab,
                                                 const uint4* __restrict__ Bp,
                                                 const float* __restrict__ bias,
                                                 const float* __restrict__ rowscale,
                                                 unsigned int* __restrict__ outB, int M) {
  int t = threadIdx.x, wid = t >> 6, lane = t & 63;
  int rowbase = blockIdx.x * 64 + wid * 16;
  int arow = rowbase + (lane & 15);
  if (arow >= M) arow = M - 1;
  constexpr int RU4 = KS * 4;

  f32x4 acc[6];
#pragma unroll
  for (int cf = 0; cf < 6; ++cf)
#pragma unroll
    for (int j = 0; j < 4; ++j) acc[cf][j] = 0.f;

#pragma unroll
  for (int ks = 0; ks < KS; ++ks) {
    uint4 a = Ab[(size_t)arow * RU4 + ks * 4 + (lane >> 4)];
    bf16x8 af = as_bf16x8(a);
#pragma unroll
    for (int cf = 0; cf < 6; ++cf) {
      uint4 b = Bp[(size_t)(ks * 6 + cf) * 64 + lane];
      acc[cf] = __builtin_amdgcn_mfma_f32_16x16x32_bf16(af, as_bf16x8(b), acc[cf], 0, 0, 0);
    }
  }

  int rows[4]; float rs[4];
#pragma unroll
  for (int i = 0; i < 4; ++i) {
    rows[i] = rowbase + (lane >> 4) * 4 + i;
    int cr = rows[i] < M ? rows[i] : M - 1;
    rs[i] = SCALE ? rowscale[cr] : 1.f;
  }
#pragma unroll
  for (int cf = 0; cf < 6; ++cf) {
    int col = cf * 16 + (lane & 15);
    float bv = BIAS ? bias[col] : 0.f;
#pragma unroll
    for (int i = 0; i < 4; ++i) {
      float v = acc[cf][i] + bv;
      if (RELU) v = fmaxf(v, 0.f);
      v *= rs[i];
      float p = __shfl_xor(v, 1);
      if (!(lane & 1) && rows[i] < M) {
        unsigned int u = (unsigned int)f2bf(v) | ((unsigned int)f2bf(p) << 16);
        outB[(size_t)rows[i] * 48 + cf * 8 + ((lane & 15) >> 1)] = u;
      }
    }
  }
}

// ---------------- GCN aggregation (bf16 gather, f32 accumulate, bf16 out) ----------------
__global__ __launch_bounds__(256) void k_agg(const unsigned int* __restrict__ hw_s,
                                             const int* __restrict__ rowp,
                                             const int* __restrict__ csr,
                                             const float* __restrict__ dinv,
                                             const float* __restrict__ bias,
                                             unsigned int* __restrict__ outB, int n) {
  int wave = threadIdx.x >> 6;
  int lane = threadIdx.x & 63;
  int node = blockIdx.x * 4 + wave;
  if (node >= n) return;
  int beg = rowp[node], end = rowp[node + 1];
  float acc0 = 0.f, acc1 = 0.f;
  bool act = lane < 48;
  int li = act ? lane : 0;
  int e = beg;
  for (; e + 8 <= end; e += 8) {
    unsigned int u0 = hw_s[(size_t)csr[e + 0] * 48 + li];
    unsigned int u1 = hw_s[(size_t)csr[e + 1] * 48 + li];
    unsigned int u2 = hw_s[(size_t)csr[e + 2] * 48 + li];
    unsigned int u3 = hw_s[(size_t)csr[e + 3] * 48 + li];
    unsigned int u4 = hw_s[(size_t)csr[e + 4] * 48 + li];
    unsigned int u5 = hw_s[(size_t)csr[e + 5] * 48 + li];
    unsigned int u6 = hw_s[(size_t)csr[e + 6] * 48 + li];
    unsigned int u7 = hw_s[(size_t)csr[e + 7] * 48 + li];
    acc0 += bflo(u0) + bflo(u1) + bflo(u2) + bflo(u3) +
            bflo(u4) + bflo(u5) + bflo(u6) + bflo(u7);
    acc1 += bfhi(u0) + bfhi(u1) + bfhi(u2) + bfhi(u3) +
            bfhi(u4) + bfhi(u5) + bfhi(u6) + bfhi(u7);
  }
  for (; e + 4 <= end; e += 4) {
    unsigned int u0 = hw_s[(size_t)csr[e + 0] * 48 + li];
    unsigned int u1 = hw_s[(size_t)csr[e + 1] * 48 + li];
    unsigned int u2 = hw_s[(size_t)csr[e + 2] * 48 + li];
    unsigned int u3 = hw_s[(size_t)csr[e + 3] * 48 + li];
    acc0 += bflo(u0) + bflo(u1) + bflo(u2) + bflo(u3);
    acc1 += bfhi(u0) + bfhi(u1) + bfhi(u2) + bfhi(u3);
  }
  for (; e < end; ++e) {
    unsigned int u = hw_s[(size_t)csr[e] * 48 + li];
    acc0 += bflo(u);
    acc1 += bfhi(u);
  }
  if (act) {
    float di = dinv[node];
    unsigned int us = hw_s[(size_t)node * 48 + li];
    float2 bv = ((const float2*)bias)[li];
    float r0 = fmaxf(di * (acc0 + bflo(us)) + bv.x, 0.f);
    float r1 = fmaxf(di * (acc1 + bfhi(us)) + bv.y, 0.f);
    outB[(size_t)node * 48 + li] = (unsigned int)f2bf(r0) | ((unsigned int)f2bf(r1) << 16);
  }
}

// ---------------- global add pool: 4 waves per graph + LDS reduce ----------------
__global__ __launch_bounds__(256) void k_pool(const unsigned int* __restrict__ hb,
                                              const int* __restrict__ batch, int n,
                                              float* __restrict__ g) {
  __shared__ float red[4][HID];
  int gr = blockIdx.x;
  int t = threadIdx.x, wv = t >> 6, lane = t & 63;
  int lo = 0, hi = n;
  while (lo < hi) { int m = (lo + hi) >> 1; if (batch[m] < gr) lo = m + 1; else hi = m; }
  int start = lo;
  hi = n;
  while (lo < hi) { int m = (lo + hi) >> 1; if (batch[m] < gr + 1) lo = m + 1; else hi = m; }
  int end = lo;
  if (lane < 48) {
    float s0 = 0.f, s1 = 0.f;
    for (int i = start + wv; i < end; i += 4) {
      unsigned int u = hb[(size_t)i * 48 + lane];
      s0 += bflo(u);
      s1 += bfhi(u);
    }
    red[wv][2 * lane] = s0;
    red[wv][2 * lane + 1] = s1;
  }
  __syncthreads();
  if (t < HID) {
    g[(size_t)gr * HID + t] = red[0][t] + red[1][t] + red[2][t] + red[3][t];
  }
}

// ---------------- decoder layer 1 (f32 VALU GEMM, M=512) ----------------
__global__ __launch_bounds__(256) void gemm_dec(const float* __restrict__ A,
                                                const float* __restrict__ W,
                                                const float* __restrict__ bias,
                                                float* __restrict__ out, int M) {
  constexpr int KC = 32;
  constexpr int APAD = KC + 4;
  __shared__ float wL[KC * 96];
  __shared__ float aL[64 * APAD];
  int t = threadIdx.x;
  int row0 = blockIdx.x * 64;
  int tr = t >> 4, tc = t & 15;
  float acc[4][6];
#pragma unroll
  for (int i = 0; i < 4; ++i)
#pragma unroll
    for (int j = 0; j < 6; ++j) acc[i][j] = 0.f;
  const float* a0p = &aL[(tr * 4 + 0) * APAD];
  const float* a1p = &aL[(tr * 4 + 1) * APAD];
  const float* a2p = &aL[(tr * 4 + 2) * APAD];
  const float* a3p = &aL[(tr * 4 + 3) * APAD];
  const float* wp = &wL[tc * 6];
  for (int ch = 0; ch < 3; ++ch) {
    {
      const float4* wg = (const float4*)(W + (size_t)ch * KC * 96);
      float4* wf = (float4*)wL;
#pragma unroll
      for (int i = 0; i < 3; ++i) wf[t + 256 * i] = wg[t + 256 * i];
    }
    {
#pragma unroll
      for (int i = 0; i < 2; ++i) {
        int idx = t + 256 * i;
        int r = idx >> 3, c4 = idx & 7;
        float4 v = make_float4(0.f, 0.f, 0.f, 0.f);
        int gr = row0 + r;
        if (gr < M) v = ((const float4*)(A + (size_t)gr * 96 + ch * KC))[c4];
        *(float4*)&aL[r * APAD + c4 * 4] = v;
      }
    }
    __syncthreads();
#pragma unroll
    for (int k = 0; k < KC; ++k) {
      float av0 = a0p[k], av1 = a1p[k], av2 = a2p[k], av3 = a3p[k];
      float b0 = wp[k * 96 + 0], b1 = wp[k * 96 + 1], b2 = wp[k * 96 + 2];
      float b3 = wp[k * 96 + 3], b4 = wp[k * 96 + 4], b5 = wp[k * 96 + 5];
      acc[0][0] += av0 * b0; acc[0][1] += av0 * b1; acc[0][2] += av0 * b2;
      acc[0][3] += av0 * b3; acc[0][4] += av0 * b4; acc[0][5] += av0 * b5;
      acc[1][0] += av1 * b0; acc[1][1] += av1 * b1; acc[1][2] += av1 * b2;
      acc[1][3] += av1 * b3; acc[1][4] += av1 * b4; acc[1][5] += av1 * b5;
      acc[2][0] += av2 * b0; acc[2][1] += av2 * b1; acc[2][2] += av2 * b2;
      acc[2][3] += av2 * b3; acc[2][4] += av2 * b4; acc[2][5] += av2 * b5;
      acc[3][0] += av3 * b0; acc[3][1] += av3 * b1; acc[3][2] += av3 * b2;
      acc[3][3] += av3 * b3; acc[3][4] += av3 * b4; acc[3][5] += av3 * b5;
    }
    __syncthreads();
  }
#pragma unroll
  for (int i = 0; i < 4; ++i) {
    int r = row0 + tr * 4 + i;
    if (r < M) {
#pragma unroll
      for (int j = 0; j < 6; ++j) {
        int c = tc * 6 + j;
        out[(size_t)r * 96 + c] = fmaxf(acc[i][j] + bias[c], 0.f);
      }
    }
  }
}

// ---------------- decoder layer 2 ----------------
__global__ void k_dec2(const float* __restrict__ g2, const float* __restrict__ W,
                       const float* __restrict__ b, float* __restrict__ out, int G) {
  int idx = blockIdx.x * 256 + threadIdx.x;
  if (idx >= G * OUTDIM) return;
  int r = idx / OUTDIM, c = idx % OUTDIM;
  float s = b[c];
  const float* row = g2 + (size_t)r * HID;
  for (int k = 0; k < HID; ++k) s += row[k] * W[k * OUTDIM + c];
  out[idx] = s;
}

extern "C" void kernel_launch(void* const* d_in, const int* in_sizes, int n_in,
                              void* d_out, int out_size, void* d_ws, size_t ws_size,
                              hipStream_t stream) {
  const float* x     = (const float*)d_in[0];
  const int*   ei    = (const int*)d_in[1];
  const int*   batch = (const int*)d_in[2];
  const float* encW0 = (const float*)d_in[3];
  const float* encb0 = (const float*)d_in[4];
  const float* encW1 = (const float*)d_in[5];
  const float* encb1 = (const float*)d_in[6];
  const float* convW = (const float*)d_in[7];
  const float* convb = (const float*)d_in[8];
  const float* decW0 = (const float*)d_in[9];
  const float* decb0 = (const float*)d_in[10];
  const float* decW1 = (const float*)d_in[11];
  const float* decb1 = (const float*)d_in[12];
  float* out = (float*)d_out;

  int n  = in_sizes[0] / INDIM;
  int E  = in_sizes[1] / 2;
  int G  = out_size / OUTDIM;
  int NC = in_sizes[7] / (HID * HID);

  const int* srcI = ei;
  const int* dstI = ei + E;

  char* w = (char*)d_ws;
  auto alloc = [&](size_t bytes) {
    char* p = w;
    w += (bytes + 255) & ~(size_t)255;
    return p;
  };
  unsigned int* xb  = (unsigned int*)alloc((size_t)n * (INDIM / 2) * 4);
  unsigned int* hbA = (unsigned int*)alloc((size_t)n * 48 * 4);
  unsigned int* hbB = (unsigned int*)alloc((size_t)n * 48 * 4);
  unsigned int* hwb = (unsigned int*)alloc((size_t)n * 48 * 4);
  uint4* wp   = (uint4*)alloc((size_t)(42 + NC * 18) * 64 * 16);
  int*   cnt   = (int*)alloc((size_t)n * 4);
  int*   rankb = (int*)alloc((size_t)E * 4);
  int*   rowp  = (int*)alloc((size_t)(n + 1) * 4);
  int*   csr   = (int*)alloc((size_t)E * 4);
  float* dinv  = (float*)alloc((size_t)n * 4);
  int*   bsum  = (int*)alloc(256 * 4);
  int*   boff  = (int*)alloc(256 * 4);
  float* g1    = (float*)alloc((size_t)G * HID * 4);
  float* g2    = (float*)alloc((size_t)G * HID * 4);

  hipMemsetAsync(cnt, 0, (size_t)n * 4, stream);

  int E4 = E / 4;                 // E = 800000, divisible by 4
  int eb4 = (E4 + 255) / 256;
  int nb = (n + 511) / 512;
  k_count<<<eb4, 256, 0, stream>>>((const int4*)dstI, E4, cnt, rankb);
  k_scanA<<<nb, 256, 0, stream>>>(cnt, n, bsum, dinv);
  k_scanB<<<1, 256, 0, stream>>>(bsum, nb, boff, rowp, n);
  k_scanC<<<nb, 256, 0, stream>>>(cnt, n, boff, rowp);
  k_fill<<<eb4, 256, 0, stream>>>((const int4*)srcI, (const int4*)dstI,
                                  (const int4*)rankb, E4, rowp, csr);

  long long xu = (long long)n * (INDIM / 2);
  k_xprep<<<(int)((xu + 255) / 256), 256, 0, stream>>>(x, xb, xu);
  k_wprep<<<42 + NC * 18, 64, 0, stream>>>(encW0, encW1, convW, wp, NC);

  int gb = (n + 63) / 64;
  mfma_gemm<4, true, true, false><<<gb, 256, 0, stream>>>(
      (const uint4*)xb, wp, encb0, nullptr, hbA, n);
  mfma_gemm<3, false, true, false><<<gb, 256, 0, stream>>>(
      (const uint4*)hbA, wp + (size_t)24 * 64, encb1, nullptr, hbB, n);
  for (int l = 0; l < NC; ++l) {
    mfma_gemm<3, false, false, true><<<gb, 256, 0, stream>>>(
        (const uint4*)hbB, wp + (size_t)(42 + l * 18) * 64, nullptr, dinv, hwb, n);
    k_agg<<<(n + 3) / 4, 256, 0, stream>>>(hwb, rowp, csr, dinv,
                                           convb + (size_t)l * HID, hbB, n);
  }
  k_pool<<<G, 256, 0, stream>>>(hbB, batch, n, g1);
  gemm_dec<<<(G + 63) / 64, 256, 0, stream>>>(g1, decW0, decb0, g2, G);
  k_dec2<<<(G * OUTDIM + 255) / 256, 256, 0, stream>>>(g2, decW1, decb1, out, G);
}

// Round 8
// 276.703 us; speedup vs baseline: 2.9961x; 1.0743x over previous
//
#include <hip/hip_runtime.h>

#define HID 96
#define INDIM 128
#define OUTDIM 10

typedef __attribute__((ext_vector_type(8))) short bf16x8;
typedef __attribute__((ext_vector_type(4))) float f32x4;

__device__ __forceinline__ unsigned short f2bf(float f) {
  unsigned int u = __float_as_uint(f);
  unsigned int r = (u + 0x7FFFu + ((u >> 16) & 1u)) >> 16;  // RNE
  return (unsigned short)r;
}
__device__ __forceinline__ bf16x8 as_bf16x8(uint4 u) {
  union { uint4 a; bf16x8 b; } c; c.a = u; return c.b;
}
__device__ __forceinline__ float bflo(unsigned int u) { return __uint_as_float(u << 16); }
__device__ __forceinline__ float bfhi(unsigned int u) { return __uint_as_float(u & 0xFFFF0000u); }

// ---------------- fused prep: x->bf16 pack | weight->B-frag | zero cnt ----------------
// blocks [0, XB): xprep (+ zero cnt for first n global threads)
// blocks [XB, XB+WB): wprep (64 active threads)
__global__ __launch_bounds__(256) void k_prep(const float* __restrict__ x,
                                              unsigned int* __restrict__ xb, long long xu,
                                              int* __restrict__ cnt, int n, int XB,
                                              const float* __restrict__ encW0,
                                              const float* __restrict__ encW1,
                                              const float* __restrict__ convW,
                                              uint4* __restrict__ wp) {
  int b = blockIdx.x;
  if (b < XB) {
    long long i = (long long)b * 256 + threadIdx.x;
    if (i < xu) {
      float2 v = ((const float2*)x)[i];
      xb[i] = (unsigned int)f2bf(v.x) | ((unsigned int)f2bf(v.y) << 16);
    }
    if (i < n) cnt[i] = 0;
    return;
  }
  int bid = b - XB;
  int lane = threadIdx.x;
  if (lane >= 64) return;
  const float* Wsrc;
  int frag;
  if (bid < 24) { Wsrc = encW0; frag = bid; }                    // K=128: 4 ks * 6 cf
  else if (bid < 42) { Wsrc = encW1; frag = bid - 24; }          // K=96: 3 * 6
  else { int c = bid - 42; Wsrc = convW + (size_t)(c / 18) * HID * HID; frag = c % 18; }
  int ks = frag / 6, cf = frag % 6;
  int col = cf * 16 + (lane & 15);
  int k0 = ks * 32 + (lane >> 4) * 8;
  unsigned int u[4];
#pragma unroll
  for (int p = 0; p < 4; ++p) {
    float lo = Wsrc[(size_t)(k0 + 2 * p) * 96 + col];
    float hi = Wsrc[(size_t)(k0 + 2 * p + 1) * 96 + col];
    u[p] = (unsigned int)f2bf(lo) | ((unsigned int)f2bf(hi) << 16);
  }
  uint4 r; r.x = u[0]; r.y = u[1]; r.z = u[2]; r.w = u[3];
  wp[(size_t)bid * 64 + lane] = r;
}

// ---------------- CSR build ----------------
__global__ void k_count(const int4* __restrict__ dst4, int E4, int* __restrict__ cnt,
                        int* __restrict__ rank) {
  int i = blockIdx.x * 256 + threadIdx.x;
  if (i >= E4) return;
  int4 d = dst4[i];
  int r0 = atomicAdd(&cnt[d.x], 1);
  int r1 = atomicAdd(&cnt[d.y], 1);
  int r2 = atomicAdd(&cnt[d.z], 1);
  int r3 = atomicAdd(&cnt[d.w], 1);
  ((int4*)rank)[i] = make_int4(r0, r1, r2, r3);
}

__global__ __launch_bounds__(256) void k_scanA(const int* __restrict__ cnt, int n,
                                               int* __restrict__ bsum,
                                               float* __restrict__ dinv) {
  __shared__ int red[256];
  int b = blockIdx.x, t = threadIdx.x;
  int base = b * 512;
  int v = 0;
  int i0 = base + t, i1 = base + 256 + t;
  if (i0 < n) { int c = cnt[i0]; v += c; dinv[i0] = rsqrtf((float)c + 1.0f); }
  if (i1 < n) { int c = cnt[i1]; v += c; dinv[i1] = rsqrtf((float)c + 1.0f); }
  red[t] = v;
  __syncthreads();
  for (int off = 128; off > 0; off >>= 1) {
    if (t < off) red[t] += red[t + off];
    __syncthreads();
  }
  if (t == 0) bsum[b] = red[0];
}

__global__ __launch_bounds__(256) void k_scanB(const int* __restrict__ bsum, int nb,
                                               int* __restrict__ boff,
                                               int* __restrict__ rowp, int n) {
  __shared__ int s[256];
  int t = threadIdx.x;
  int v = (t < nb) ? bsum[t] : 0;
  s[t] = v;
  __syncthreads();
  for (int off = 1; off < 256; off <<= 1) {
    int u = (t >= off) ? s[t - off] : 0;
    __syncthreads();
    s[t] += u;
    __syncthreads();
  }
  if (t < nb) boff[t] = s[t] - v;
  if (t == 255) rowp[n] = s[255];
}

__global__ __launch_bounds__(256) void k_scanC(const int* __restrict__ cnt, int n,
                                               const int* __restrict__ boff,
                                               int* __restrict__ rowp) {
  __shared__ int s[256];
  int b = blockIdx.x, t = threadIdx.x;
  int base = b * 512;
  int i0 = base + 2 * t, i1 = i0 + 1;
  int c0 = (i0 < n) ? cnt[i0] : 0;
  int c1 = (i1 < n) ? cnt[i1] : 0;
  int pair = c0 + c1;
  s[t] = pair;
  __syncthreads();
  for (int off = 1; off < 256; off <<= 1) {
    int u = (t >= off) ? s[t - off] : 0;
    __syncthreads();
    s[t] += u;
    __syncthreads();
  }
  int excl = s[t] - pair + boff[b];
  if (i0 < n) rowp[i0] = excl;
  if (i1 < n) rowp[i1] = excl + c0;
}

__global__ void k_fill(const int4* __restrict__ src4, const int4* __restrict__ dst4,
                       const int4* __restrict__ rank4, int E4,
                       const int* __restrict__ rowp, int* __restrict__ csr) {
  int i = blockIdx.x * 256 + threadIdx.x;
  if (i >= E4) return;
  int4 s = src4[i];
  int4 d = dst4[i];
  int4 r = rank4[i];
  csr[rowp[d.x] + r.x] = s.x;
  csr[rowp[d.y] + r.y] = s.y;
  csr[rowp[d.z] + r.z] = s.z;
  csr[rowp[d.w] + r.w] = s.w;
}

// ---------------- MFMA GEMM ----------------
template <int KS, bool RELU, bool BIAS, bool SCALE>
__global__ __launch_bounds__(256) void mfma_gemm(const uint4* __restrict__ Ab,
                                                 const uint4* __restrict__ Bp,
                                                 const float* __restrict__ bias,
                                                 const float* __restrict__ rowscale,
                                                 unsigned int* __restrict__ outB, int M) {
  int t = threadIdx.x, wid = t >> 6, lane = t & 63;
  int rowbase = blockIdx.x * 64 + wid * 16;
  int arow = rowbase + (lane & 15);
  if (arow >= M) arow = M - 1;
  constexpr int RU4 = KS * 4;

  f32x4 acc[6];
#pragma unroll
  for (int cf = 0; cf < 6; ++cf)
#pragma unroll
    for (int j = 0; j < 4; ++j) acc[cf][j] = 0.f;

#pragma unroll
  for (int ks = 0; ks < KS; ++ks) {
    uint4 a = Ab[(size_t)arow * RU4 + ks * 4 + (lane >> 4)];
    bf16x8 af = as_bf16x8(a);
#pragma unroll
    for (int cf = 0; cf < 6; ++cf) {
      uint4 b = Bp[(size_t)(ks * 6 + cf) * 64 + lane];
      acc[cf] = __builtin_amdgcn_mfma_f32_16x16x32_bf16(af, as_bf16x8(b), acc[cf], 0, 0, 0);
    }
  }

  int rows[4]; float rs[4];
#pragma unroll
  for (int i = 0; i < 4; ++i) {
    rows[i] = rowbase + (lane >> 4) * 4 + i;
    int cr = rows[i] < M ? rows[i] : M - 1;
    rs[i] = SCALE ? rowscale[cr] : 1.f;
  }
#pragma unroll
  for (int cf = 0; cf < 6; ++cf) {
    int col = cf * 16 + (lane & 15);
    float bv = BIAS ? bias[col] : 0.f;
#pragma unroll
    for (int i = 0; i < 4; ++i) {
      float v = acc[cf][i] + bv;
      if (RELU) v = fmaxf(v, 0.f);
      v *= rs[i];
      float p = __shfl_xor(v, 1);
      if (!(lane & 1) && rows[i] < M) {
        unsigned int u = (unsigned int)f2bf(v) | ((unsigned int)f2bf(p) << 16);
        outB[(size_t)rows[i] * 48 + cf * 8 + ((lane & 15) >> 1)] = u;
      }
    }
  }
}

// ---------------- GCN aggregation (bf16 gather, f32 accumulate, bf16 out) ----------------
__global__ __launch_bounds__(256) void k_agg(const unsigned int* __restrict__ hw_s,
                                             const int* __restrict__ rowp,
                                             const int* __restrict__ csr,
                                             const float* __restrict__ dinv,
                                             const float* __restrict__ bias,
                                             unsigned int* __restrict__ outB, int n) {
  int wave = threadIdx.x >> 6;
  int lane = threadIdx.x & 63;
  int node = blockIdx.x * 4 + wave;
  if (node >= n) return;
  int beg = rowp[node], end = rowp[node + 1];
  float acc0 = 0.f, acc1 = 0.f;
  bool act = lane < 48;
  int li = act ? lane : 0;
  int e = beg;
  for (; e + 8 <= end; e += 8) {
    unsigned int u0 = hw_s[(size_t)csr[e + 0] * 48 + li];
    unsigned int u1 = hw_s[(size_t)csr[e + 1] * 48 + li];
    unsigned int u2 = hw_s[(size_t)csr[e + 2] * 48 + li];
    unsigned int u3 = hw_s[(size_t)csr[e + 3] * 48 + li];
    unsigned int u4 = hw_s[(size_t)csr[e + 4] * 48 + li];
    unsigned int u5 = hw_s[(size_t)csr[e + 5] * 48 + li];
    unsigned int u6 = hw_s[(size_t)csr[e + 6] * 48 + li];
    unsigned int u7 = hw_s[(size_t)csr[e + 7] * 48 + li];
    acc0 += bflo(u0) + bflo(u1) + bflo(u2) + bflo(u3) +
            bflo(u4) + bflo(u5) + bflo(u6) + bflo(u7);
    acc1 += bfhi(u0) + bfhi(u1) + bfhi(u2) + bfhi(u3) +
            bfhi(u4) + bfhi(u5) + bfhi(u6) + bfhi(u7);
  }
  for (; e + 4 <= end; e += 4) {
    unsigned int u0 = hw_s[(size_t)csr[e + 0] * 48 + li];
    unsigned int u1 = hw_s[(size_t)csr[e + 1] * 48 + li];
    unsigned int u2 = hw_s[(size_t)csr[e + 2] * 48 + li];
    unsigned int u3 = hw_s[(size_t)csr[e + 3] * 48 + li];
    acc0 += bflo(u0) + bflo(u1) + bflo(u2) + bflo(u3);
    acc1 += bfhi(u0) + bfhi(u1) + bfhi(u2) + bfhi(u3);
  }
  for (; e < end; ++e) {
    unsigned int u = hw_s[(size_t)csr[e] * 48 + li];
    acc0 += bflo(u);
    acc1 += bfhi(u);
  }
  if (act) {
    float di = dinv[node];
    unsigned int us = hw_s[(size_t)node * 48 + li];
    float2 bv = ((const float2*)bias)[li];
    float r0 = fmaxf(di * (acc0 + bflo(us)) + bv.x, 0.f);
    float r1 = fmaxf(di * (acc1 + bfhi(us)) + bv.y, 0.f);
    outB[(size_t)node * 48 + li] = (unsigned int)f2bf(r0) | ((unsigned int)f2bf(r1) << 16);
  }
}

// ---------------- fused head: global add pool + decoder MLP ----------------
// One block per graph: pool h rows (4 waves) -> g1 (LDS) -> g2 = relu(g1@W0+b0)
// (W0 LDS-staged) -> out = g2@W1+b1.
__global__ __launch_bounds__(256) void k_head(const unsigned int* __restrict__ hb,
                                              const int* __restrict__ batch, int n,
                                              const float* __restrict__ W0,
                                              const float* __restrict__ b0,
                                              const float* __restrict__ W1,
                                              const float* __restrict__ b1,
                                              float* __restrict__ out) {
  __shared__ float w0L[HID * HID];  // 36 KB
  __shared__ float red[4][HID];
  __shared__ float g1L[HID];
  __shared__ float g2L[HID];
  int gr = blockIdx.x;
  int t = threadIdx.x, wv = t >> 6, lane = t & 63;

  // stage W0 (36 KB, contiguous float4)
  for (int i = t; i < HID * HID / 4; i += 256) ((float4*)w0L)[i] = ((const float4*)W0)[i];

  // graph row range via binary search (batch sorted)
  int lo = 0, hi = n;
  while (lo < hi) { int m = (lo + hi) >> 1; if (batch[m] < gr) lo = m + 1; else hi = m; }
  int start = lo;
  hi = n;
  while (lo < hi) { int m = (lo + hi) >> 1; if (batch[m] < gr + 1) lo = m + 1; else hi = m; }
  int end = lo;

  if (lane < 48) {
    float s0 = 0.f, s1 = 0.f;
    for (int i = start + wv; i < end; i += 4) {
      unsigned int u = hb[(size_t)i * 48 + lane];
      s0 += bflo(u);
      s1 += bfhi(u);
    }
    red[wv][2 * lane] = s0;
    red[wv][2 * lane + 1] = s1;
  }
  __syncthreads();
  if (t < HID) g1L[t] = red[0][t] + red[1][t] + red[2][t] + red[3][t];
  __syncthreads();
  if (t < HID) {
    float a = b0[t];
    for (int k = 0; k < HID; ++k) a += g1L[k] * w0L[k * HID + t];
    g2L[t] = fmaxf(a, 0.f);
  }
  __syncthreads();
  if (t < OUTDIM) {
    float a = b1[t];
    for (int k = 0; k < HID; ++k) a += g2L[k] * W1[k * OUTDIM + t];
    out[(size_t)gr * OUTDIM + t] = a;
  }
}

extern "C" void kernel_launch(void* const* d_in, const int* in_sizes, int n_in,
                              void* d_out, int out_size, void* d_ws, size_t ws_size,
                              hipStream_t stream) {
  const float* x     = (const float*)d_in[0];
  const int*   ei    = (const int*)d_in[1];
  const int*   batch = (const int*)d_in[2];
  const float* encW0 = (const float*)d_in[3];
  const float* encb0 = (const float*)d_in[4];
  const float* encW1 = (const float*)d_in[5];
  const float* encb1 = (const float*)d_in[6];
  const float* convW = (const float*)d_in[7];
  const float* convb = (const float*)d_in[8];
  const float* decW0 = (const float*)d_in[9];
  const float* decb0 = (const float*)d_in[10];
  const float* decW1 = (const float*)d_in[11];
  const float* decb1 = (const float*)d_in[12];
  float* out = (float*)d_out;

  int n  = in_sizes[0] / INDIM;
  int E  = in_sizes[1] / 2;
  int G  = out_size / OUTDIM;
  int NC = in_sizes[7] / (HID * HID);

  const int* srcI = ei;
  const int* dstI = ei + E;

  char* w = (char*)d_ws;
  auto alloc = [&](size_t bytes) {
    char* p = w;
    w += (bytes + 255) & ~(size_t)255;
    return p;
  };
  unsigned int* xb  = (unsigned int*)alloc((size_t)n * (INDIM / 2) * 4);
  unsigned int* hbA = (unsigned int*)alloc((size_t)n * 48 * 4);
  unsigned int* hbB = (unsigned int*)alloc((size_t)n * 48 * 4);
  unsigned int* hwb = (unsigned int*)alloc((size_t)n * 48 * 4);
  uint4* wp   = (uint4*)alloc((size_t)(42 + NC * 18) * 64 * 16);
  int*   cnt   = (int*)alloc((size_t)n * 4);
  int*   rankb = (int*)alloc((size_t)E * 4);
  int*   rowp  = (int*)alloc((size_t)(n + 1) * 4);
  int*   csr   = (int*)alloc((size_t)E * 4);
  float* dinv  = (float*)alloc((size_t)n * 4);
  int*   bsum  = (int*)alloc(256 * 4);
  int*   boff  = (int*)alloc(256 * 4);

  long long xu = (long long)n * (INDIM / 2);
  int XB = (int)((xu + 255) / 256);
  int WB = 42 + NC * 18;
  // fused prep: packs x to bf16, preps weight fragments, zeroes cnt
  k_prep<<<XB + WB, 256, 0, stream>>>(x, xb, xu, cnt, n, XB, encW0, encW1, convW, wp);

  int E4 = E / 4;                 // E = 800000, divisible by 4
  int eb4 = (E4 + 255) / 256;
  int nb = (n + 511) / 512;
  k_count<<<eb4, 256, 0, stream>>>((const int4*)dstI, E4, cnt, rankb);
  k_scanA<<<nb, 256, 0, stream>>>(cnt, n, bsum, dinv);
  k_scanB<<<1, 256, 0, stream>>>(bsum, nb, boff, rowp, n);
  k_scanC<<<nb, 256, 0, stream>>>(cnt, n, boff, rowp);
  k_fill<<<eb4, 256, 0, stream>>>((const int4*)srcI, (const int4*)dstI,
                                  (const int4*)rankb, E4, rowp, csr);

  int gb = (n + 63) / 64;
  mfma_gemm<4, true, true, false><<<gb, 256, 0, stream>>>(
      (const uint4*)xb, wp, encb0, nullptr, hbA, n);
  mfma_gemm<3, false, true, false><<<gb, 256, 0, stream>>>(
      (const uint4*)hbA, wp + (size_t)24 * 64, encb1, nullptr, hbB, n);
  for (int l = 0; l < NC; ++l) {
    mfma_gemm<3, false, false, true><<<gb, 256, 0, stream>>>(
        (const uint4*)hbB, wp + (size_t)(42 + l * 18) * 64, nullptr, dinv, hwb, n);
    k_agg<<<(n + 3) / 4, 256, 0, stream>>>(hwb, rowp, csr, dinv,
                                           convb + (size_t)l * HID, hbB, n);
  }
  k_head<<<G, 256, 0, stream>>>(hbB, batch, n, decW0, decb0, decW1, decb1, out);
}

// Round 9
// 270.236 us; speedup vs baseline: 3.0678x; 1.0239x over previous
//
#include <hip/hip_runtime.h>

#define HID 96
#define INDIM 128
#define OUTDIM 10

typedef __attribute__((ext_vector_type(8))) short bf16x8;
typedef __attribute__((ext_vector_type(4))) float f32x4;

__device__ __forceinline__ unsigned short f2bf(float f) {
  unsigned int u = __float_as_uint(f);
  unsigned int r = (u + 0x7FFFu + ((u >> 16) & 1u)) >> 16;  // RNE
  return (unsigned short)r;
}
__device__ __forceinline__ bf16x8 as_bf16x8(uint4 u) {
  union { uint4 a; bf16x8 b; } c; c.a = u; return c.b;
}
__device__ __forceinline__ float bflo(unsigned int u) { return __uint_as_float(u << 16); }
__device__ __forceinline__ float bfhi(unsigned int u) { return __uint_as_float(u & 0xFFFF0000u); }

// ---------------- fused prep: x->bf16 pack | weight->B-frag | zero cnt ----------------
__global__ __launch_bounds__(256) void k_prep(const float* __restrict__ x,
                                              unsigned int* __restrict__ xb, long long xu,
                                              int* __restrict__ cnt, int n, int XB,
                                              const float* __restrict__ encW0,
                                              const float* __restrict__ encW1,
                                              const float* __restrict__ convW,
                                              uint4* __restrict__ wp) {
  int b = blockIdx.x;
  if (b < XB) {
    long long i = (long long)b * 256 + threadIdx.x;
    if (i < xu) {
      float2 v = ((const float2*)x)[i];
      xb[i] = (unsigned int)f2bf(v.x) | ((unsigned int)f2bf(v.y) << 16);
    }
    if (i < n) cnt[i] = 0;
    return;
  }
  int bid = b - XB;
  int lane = threadIdx.x;
  if (lane >= 64) return;
  const float* Wsrc;
  int frag;
  if (bid < 24) { Wsrc = encW0; frag = bid; }                    // K=128: 4 ks * 6 cf
  else if (bid < 42) { Wsrc = encW1; frag = bid - 24; }          // K=96: 3 * 6
  else { int c = bid - 42; Wsrc = convW + (size_t)(c / 18) * HID * HID; frag = c % 18; }
  int ks = frag / 6, cf = frag % 6;
  int col = cf * 16 + (lane & 15);
  int k0 = ks * 32 + (lane >> 4) * 8;
  unsigned int u[4];
#pragma unroll
  for (int p = 0; p < 4; ++p) {
    float lo = Wsrc[(size_t)(k0 + 2 * p) * 96 + col];
    float hi = Wsrc[(size_t)(k0 + 2 * p + 1) * 96 + col];
    u[p] = (unsigned int)f2bf(lo) | ((unsigned int)f2bf(hi) << 16);
  }
  uint4 r; r.x = u[0]; r.y = u[1]; r.z = u[2]; r.w = u[3];
  wp[(size_t)bid * 64 + lane] = r;
}

// ---------------- device bodies for fused stages ----------------
__device__ __forceinline__ void count_body(int blk, const int4* __restrict__ dst4, int E4,
                                           int* __restrict__ cnt, int* __restrict__ rank) {
  int i = blk * 256 + threadIdx.x;
  if (i >= E4) return;
  int4 d = dst4[i];
  int r0 = atomicAdd(&cnt[d.x], 1);
  int r1 = atomicAdd(&cnt[d.y], 1);
  int r2 = atomicAdd(&cnt[d.z], 1);
  int r3 = atomicAdd(&cnt[d.w], 1);
  ((int4*)rank)[i] = make_int4(r0, r1, r2, r3);
}

__device__ __forceinline__ void scanA_body(int blk, const int* __restrict__ cnt, int n,
                                           int* __restrict__ bsum, float* __restrict__ dinv) {
  __shared__ int red[256];
  int t = threadIdx.x;
  int base = blk * 512;
  int v = 0;
  int i0 = base + t, i1 = base + 256 + t;
  if (i0 < n) { int c = cnt[i0]; v += c; dinv[i0] = rsqrtf((float)c + 1.0f); }
  if (i1 < n) { int c = cnt[i1]; v += c; dinv[i1] = rsqrtf((float)c + 1.0f); }
  red[t] = v;
  __syncthreads();
  for (int off = 128; off > 0; off >>= 1) {
    if (t < off) red[t] += red[t + off];
    __syncthreads();
  }
  if (t == 0) bsum[blk] = red[0];
}

__device__ __forceinline__ void scanC_body(int blk, const int* __restrict__ cnt, int n,
                                           const int* __restrict__ boff,
                                           int* __restrict__ rowp) {
  __shared__ int s[256];
  int t = threadIdx.x;
  int base = blk * 512;
  int i0 = base + 2 * t, i1 = i0 + 1;
  int c0 = (i0 < n) ? cnt[i0] : 0;
  int c1 = (i1 < n) ? cnt[i1] : 0;
  int pair = c0 + c1;
  s[t] = pair;
  __syncthreads();
  for (int off = 1; off < 256; off <<= 1) {
    int u = (t >= off) ? s[t - off] : 0;
    __syncthreads();
    s[t] += u;
    __syncthreads();
  }
  int excl = s[t] - pair + boff[blk];
  if (i0 < n) rowp[i0] = excl;
  if (i1 < n) rowp[i1] = excl + c0;
}

// ---------------- MFMA GEMM body ----------------
template <int KS, bool RELU, bool BIAS, bool SCALE>
__device__ __forceinline__ void gemm_body(int blk, const uint4* __restrict__ Ab,
                                          const uint4* __restrict__ Bp,
                                          const float* __restrict__ bias,
                                          const float* __restrict__ rowscale,
                                          unsigned int* __restrict__ outB, int M) {
  int t = threadIdx.x, wid = t >> 6, lane = t & 63;
  int rowbase = blk * 64 + wid * 16;
  int arow = rowbase + (lane & 15);
  if (arow >= M) arow = M - 1;
  constexpr int RU4 = KS * 4;

  f32x4 acc[6];
#pragma unroll
  for (int cf = 0; cf < 6; ++cf)
#pragma unroll
    for (int j = 0; j < 4; ++j) acc[cf][j] = 0.f;

#pragma unroll
  for (int ks = 0; ks < KS; ++ks) {
    uint4 a = Ab[(size_t)arow * RU4 + ks * 4 + (lane >> 4)];
    bf16x8 af = as_bf16x8(a);
#pragma unroll
    for (int cf = 0; cf < 6; ++cf) {
      uint4 b = Bp[(size_t)(ks * 6 + cf) * 64 + lane];
      acc[cf] = __builtin_amdgcn_mfma_f32_16x16x32_bf16(af, as_bf16x8(b), acc[cf], 0, 0, 0);
    }
  }

  int rows[4]; float rs[4];
#pragma unroll
  for (int i = 0; i < 4; ++i) {
    rows[i] = rowbase + (lane >> 4) * 4 + i;
    int cr = rows[i] < M ? rows[i] : M - 1;
    rs[i] = SCALE ? rowscale[cr] : 1.f;
  }
#pragma unroll
  for (int cf = 0; cf < 6; ++cf) {
    int col = cf * 16 + (lane & 15);
    float bv = BIAS ? bias[col] : 0.f;
#pragma unroll
    for (int i = 0; i < 4; ++i) {
      float v = acc[cf][i] + bv;
      if (RELU) v = fmaxf(v, 0.f);
      v *= rs[i];
      float p = __shfl_xor(v, 1);
      if (!(lane & 1) && rows[i] < M) {
        unsigned int u = (unsigned int)f2bf(v) | ((unsigned int)f2bf(p) << 16);
        outB[(size_t)rows[i] * 48 + cf * 8 + ((lane & 15) >> 1)] = u;
      }
    }
  }
}

// ---------------- fused kernels: independent halves by block range ----------------
__global__ __launch_bounds__(256) void k_count_enc1(
    const int4* __restrict__ dst4, int E4, int* __restrict__ cnt, int* __restrict__ rank,
    int CB, const uint4* __restrict__ Ab, const uint4* __restrict__ Bp,
    const float* __restrict__ bias, unsigned int* __restrict__ outB, int M) {
  int b = blockIdx.x;
  if (b < CB) count_body(b, dst4, E4, cnt, rank);
  else gemm_body<4, true, true, false>(b - CB, Ab, Bp, bias, nullptr, outB, M);
}

__global__ __launch_bounds__(256) void k_scanA_enc2(
    const int* __restrict__ cnt, int n, int* __restrict__ bsum, float* __restrict__ dinv,
    int SB, const uint4* __restrict__ Ab, const uint4* __restrict__ Bp,
    const float* __restrict__ bias, unsigned int* __restrict__ outB, int M) {
  int b = blockIdx.x;
  if (b < SB) scanA_body(b, cnt, n, bsum, dinv);
  else gemm_body<3, false, true, false>(b - SB, Ab, Bp, bias, nullptr, outB, M);
}

__global__ __launch_bounds__(256) void k_scanC_conv(
    const int* __restrict__ cnt, int n, const int* __restrict__ boff,
    int* __restrict__ rowp, int SB, const uint4* __restrict__ Ab,
    const uint4* __restrict__ Bp, const float* __restrict__ rowscale,
    unsigned int* __restrict__ outB, int M) {
  int b = blockIdx.x;
  if (b < SB) scanC_body(b, cnt, n, boff, rowp);
  else gemm_body<3, false, false, true>(b - SB, Ab, Bp, nullptr, rowscale, outB, M);
}

// standalone gemm for conv layers >= 1
template <int KS, bool RELU, bool BIAS, bool SCALE>
__global__ __launch_bounds__(256) void mfma_gemm(const uint4* __restrict__ Ab,
                                                 const uint4* __restrict__ Bp,
                                                 const float* __restrict__ bias,
                                                 const float* __restrict__ rowscale,
                                                 unsigned int* __restrict__ outB, int M) {
  gemm_body<KS, RELU, BIAS, SCALE>(blockIdx.x, Ab, Bp, bias, rowscale, outB, M);
}

__global__ __launch_bounds__(256) void k_scanB(const int* __restrict__ bsum, int nb,
                                               int* __restrict__ boff,
                                               int* __restrict__ rowp, int n) {
  __shared__ int s[256];
  int t = threadIdx.x;
  int v = (t < nb) ? bsum[t] : 0;
  s[t] = v;
  __syncthreads();
  for (int off = 1; off < 256; off <<= 1) {
    int u = (t >= off) ? s[t - off] : 0;
    __syncthreads();
    s[t] += u;
    __syncthreads();
  }
  if (t < nb) boff[t] = s[t] - v;
  if (t == 255) rowp[n] = s[255];
}

__global__ void k_fill(const int4* __restrict__ src4, const int4* __restrict__ dst4,
                       const int4* __restrict__ rank4, int E4,
                       const int* __restrict__ rowp, int* __restrict__ csr) {
  int i = blockIdx.x * 256 + threadIdx.x;
  if (i >= E4) return;
  int4 s = src4[i];
  int4 d = dst4[i];
  int4 r = rank4[i];
  csr[rowp[d.x] + r.x] = s.x;
  csr[rowp[d.y] + r.y] = s.y;
  csr[rowp[d.z] + r.z] = s.z;
  csr[rowp[d.w] + r.w] = s.w;
}

// ---------------- GCN aggregation (bf16 gather, f32 accumulate, bf16 out) ----------------
// 16-deep edge unroll: 16 line-gathers in flight per wave (latency*MLP limited).
__global__ __launch_bounds__(256) void k_agg(const unsigned int* __restrict__ hw_s,
                                             const int* __restrict__ rowp,
                                             const int* __restrict__ csr,
                                             const float* __restrict__ dinv,
                                             const float* __restrict__ bias,
                                             unsigned int* __restrict__ outB, int n) {
  int wave = threadIdx.x >> 6;
  int lane = threadIdx.x & 63;
  int node = blockIdx.x * 4 + wave;
  if (node >= n) return;
  int beg = rowp[node], end = rowp[node + 1];
  float acc0 = 0.f, acc1 = 0.f;
  bool act = lane < 48;
  int li = act ? lane : 0;
  int e = beg;
  for (; e + 16 <= end; e += 16) {
    unsigned int uu[16];
#pragma unroll
    for (int j = 0; j < 16; ++j) uu[j] = hw_s[(size_t)csr[e + j] * 48 + li];
    float a0 = 0.f, a1 = 0.f;
#pragma unroll
    for (int j = 0; j < 16; ++j) { a0 += bflo(uu[j]); a1 += bfhi(uu[j]); }
    acc0 += a0; acc1 += a1;
  }
  for (; e + 4 <= end; e += 4) {
    unsigned int u0 = hw_s[(size_t)csr[e + 0] * 48 + li];
    unsigned int u1 = hw_s[(size_t)csr[e + 1] * 48 + li];
    unsigned int u2 = hw_s[(size_t)csr[e + 2] * 48 + li];
    unsigned int u3 = hw_s[(size_t)csr[e + 3] * 48 + li];
    acc0 += bflo(u0) + bflo(u1) + bflo(u2) + bflo(u3);
    acc1 += bfhi(u0) + bfhi(u1) + bfhi(u2) + bfhi(u3);
  }
  for (; e < end; ++e) {
    unsigned int u = hw_s[(size_t)csr[e] * 48 + li];
    acc0 += bflo(u);
    acc1 += bfhi(u);
  }
  if (act) {
    float di = dinv[node];
    unsigned int us = hw_s[(size_t)node * 48 + li];
    float2 bv = ((const float2*)bias)[li];
    float r0 = fmaxf(di * (acc0 + bflo(us)) + bv.x, 0.f);
    float r1 = fmaxf(di * (acc1 + bfhi(us)) + bv.y, 0.f);
    outB[(size_t)node * 48 + li] = (unsigned int)f2bf(r0) | ((unsigned int)f2bf(r1) << 16);
  }
}

// ---------------- fused head: global add pool + decoder MLP ----------------
__global__ __launch_bounds__(256) void k_head(const unsigned int* __restrict__ hb,
                                              const int* __restrict__ batch, int n,
                                              const float* __restrict__ W0,
                                              const float* __restrict__ b0,
                                              const float* __restrict__ W1,
                                              const float* __restrict__ b1,
                                              float* __restrict__ out) {
  __shared__ float w0L[HID * HID];  // 36 KB
  __shared__ float red[4][HID];
  __shared__ float g1L[HID];
  __shared__ float g2L[HID];
  int gr = blockIdx.x;
  int t = threadIdx.x, wv = t >> 6, lane = t & 63;

  for (int i = t; i < HID * HID / 4; i += 256) ((float4*)w0L)[i] = ((const float4*)W0)[i];

  int lo = 0, hi = n;
  while (lo < hi) { int m = (lo + hi) >> 1; if (batch[m] < gr) lo = m + 1; else hi = m; }
  int start = lo;
  hi = n;
  while (lo < hi) { int m = (lo + hi) >> 1; if (batch[m] < gr + 1) lo = m + 1; else hi = m; }
  int end = lo;

  if (lane < 48) {
    float s0 = 0.f, s1 = 0.f;
    for (int i = start + wv; i < end; i += 4) {
      unsigned int u = hb[(size_t)i * 48 + lane];
      s0 += bflo(u);
      s1 += bfhi(u);
    }
    red[wv][2 * lane] = s0;
    red[wv][2 * lane + 1] = s1;
  }
  __syncthreads();
  if (t < HID) g1L[t] = red[0][t] + red[1][t] + red[2][t] + red[3][t];
  __syncthreads();
  if (t < HID) {
    float a = b0[t];
    for (int k = 0; k < HID; ++k) a += g1L[k] * w0L[k * HID + t];
    g2L[t] = fmaxf(a, 0.f);
  }
  __syncthreads();
  if (t < OUTDIM) {
    float a = b1[t];
    for (int k = 0; k < HID; ++k) a += g2L[k] * W1[k * OUTDIM + t];
    out[(size_t)gr * OUTDIM + t] = a;
  }
}

extern "C" void kernel_launch(void* const* d_in, const int* in_sizes, int n_in,
                              void* d_out, int out_size, void* d_ws, size_t ws_size,
                              hipStream_t stream) {
  const float* x     = (const float*)d_in[0];
  const int*   ei    = (const int*)d_in[1];
  const int*   batch = (const int*)d_in[2];
  const float* encW0 = (const float*)d_in[3];
  const float* encb0 = (const float*)d_in[4];
  const float* encW1 = (const float*)d_in[5];
  const float* encb1 = (const float*)d_in[6];
  const float* convW = (const float*)d_in[7];
  const float* convb = (const float*)d_in[8];
  const float* decW0 = (const float*)d_in[9];
  const float* decb0 = (const float*)d_in[10];
  const float* decW1 = (const float*)d_in[11];
  const float* decb1 = (const float*)d_in[12];
  float* out = (float*)d_out;

  int n  = in_sizes[0] / INDIM;
  int E  = in_sizes[1] / 2;
  int G  = out_size / OUTDIM;
  int NC = in_sizes[7] / (HID * HID);

  const int* srcI = ei;
  const int* dstI = ei + E;

  char* w = (char*)d_ws;
  auto alloc = [&](size_t bytes) {
    char* p = w;
    w += (bytes + 255) & ~(size_t)255;
    return p;
  };
  unsigned int* xb  = (unsigned int*)alloc((size_t)n * (INDIM / 2) * 4);
  unsigned int* hbA = (unsigned int*)alloc((size_t)n * 48 * 4);
  unsigned int* hbB = (unsigned int*)alloc((size_t)n * 48 * 4);
  unsigned int* hwb = (unsigned int*)alloc((size_t)n * 48 * 4);
  uint4* wp   = (uint4*)alloc((size_t)(42 + NC * 18) * 64 * 16);
  int*   cnt   = (int*)alloc((size_t)n * 4);
  int*   rankb = (int*)alloc((size_t)E * 4);
  int*   rowp  = (int*)alloc((size_t)(n + 1) * 4);
  int*   csr   = (int*)alloc((size_t)E * 4);
  float* dinv  = (float*)alloc((size_t)n * 4);
  int*   bsum  = (int*)alloc(256 * 4);
  int*   boff  = (int*)alloc(256 * 4);

  long long xu = (long long)n * (INDIM / 2);
  int XB = (int)((xu + 255) / 256);
  int WB = 42 + NC * 18;
  k_prep<<<XB + WB, 256, 0, stream>>>(x, xb, xu, cnt, n, XB, encW0, encW1, convW, wp);

  int E4 = E / 4;                 // E = 800000, divisible by 4
  int eb4 = (E4 + 255) / 256;
  int nb = (n + 511) / 512;
  int gb = (n + 63) / 64;

  // count || encoder gemm1
  k_count_enc1<<<eb4 + gb, 256, 0, stream>>>((const int4*)dstI, E4, cnt, rankb, eb4,
                                             (const uint4*)xb, wp, encb0, hbA, n);
  // scanA(+dinv) || encoder gemm2
  k_scanA_enc2<<<nb + gb, 256, 0, stream>>>(cnt, n, bsum, dinv, nb,
                                            (const uint4*)hbA, wp + (size_t)24 * 64,
                                            encb1, hbB, n);
  k_scanB<<<1, 256, 0, stream>>>(bsum, nb, boff, rowp, n);
  // scanC || conv gemm l=0
  k_scanC_conv<<<nb + gb, 256, 0, stream>>>(cnt, n, boff, rowp, nb,
                                            (const uint4*)hbB, wp + (size_t)42 * 64,
                                            dinv, hwb, n);
  k_fill<<<eb4, 256, 0, stream>>>((const int4*)srcI, (const int4*)dstI,
                                  (const int4*)rankb, E4, rowp, csr);
  k_agg<<<(n + 3) / 4, 256, 0, stream>>>(hwb, rowp, csr, dinv, convb, hbB, n);

  for (int l = 1; l < NC; ++l) {
    mfma_gemm<3, false, false, true><<<gb, 256, 0, stream>>>(
        (const uint4*)hbB, wp + (size_t)(42 + l * 18) * 64, nullptr, dinv, hwb, n);
    k_agg<<<(n + 3) / 4, 256, 0, stream>>>(hwb, rowp, csr, dinv,
                                           convb + (size_t)l * HID, hbB, n);
  }
  k_head<<<G, 256, 0, stream>>>(hbB, batch, n, decW0, decb0, decW1, decb1, out);
}